// Round 2
// baseline (597.448 us; speedup 1.0000x reference)
//
#include <hip/hip_runtime.h>
#include <hip/hip_bf16.h>
#include <math.h>

// ROSA QKV layer, fp32.
//  K1 k_proj      : q/k/v logits = x @ {wq,wk,wv}, 16 rows/block, k-unrolled x4
//  K1b k_softmax64: per-head softmax(logits/tau) over Hd=64, in place
//  K2 k_qkt       : causal QK^T directly into skewed coords S[d][c] = A[c+d][c],
//                   LDS fragments XOR-swizzled for conflict-free ds_read_b128
//  K3 k_scan      : y[c] = x[c]*(y[c-1]+1) along skewed rows, wave shfl-scan
//  K4 k_attn      : gather skewed->normal tile, LANE-PARALLEL online softmax
//                   (lane = s), p round-trip through LDS, PV via broadcast
//                   float4 (lane = channel), fused per-head output projection
//
// ws layout: q 4MB | k 4MB | v 4MB | S 64MB  (total 76MB)

#define TT 1024
#define BB 2
#define HH 8
#define HD 64
#define DD 512
#define BH (BB*HH)

constexpr float INV_TAU = 10.0f;

// XOR swizzle: bijective in j per row, keeps float4 (bits 0-1) intact,
// spreads rows 4*r apart across banks (16 fragment rows -> <=2-way conflict).
#define SW(r, j) ((j) ^ ((((r) >> 2) & 7) << 2))

// ---------------- K1: projection GEMM (fp32) ----------------
// 256 threads: 16 rows x 512 cols; thread t owns cols t and t+256.
__global__ __launch_bounds__(256) void k_proj(const float* __restrict__ x,
                                              const float* __restrict__ wq,
                                              const float* __restrict__ wk,
                                              const float* __restrict__ wv,
                                              float* __restrict__ oq,
                                              float* __restrict__ ok,
                                              float* __restrict__ ov) {
  __shared__ float xs[16][512];
  const int tid = threadIdx.x;
  const int arr = blockIdx.y;
  const float* __restrict__ W = (arr == 0) ? wq : ((arr == 1) ? wk : wv);
  float* __restrict__ out = (arr == 0) ? oq : ((arr == 1) ? ok : ov);
  const int row0 = blockIdx.x * 16;

  for (int idx = tid; idx < 16 * 512; idx += 256) {
    int r = idx >> 9, c = idx & 511;
    xs[r][c] = x[(size_t)(row0 + r) * 512 + c];
  }
  __syncthreads();

  float acc0[16] = {};
  float acc1[16] = {};
  for (int k = 0; k < 512; k += 4) {
    float wa[4], wb[4];
#pragma unroll
    for (int jj = 0; jj < 4; ++jj) {
      wa[jj] = W[(size_t)(k + jj) * 512 + tid];
      wb[jj] = W[(size_t)(k + jj) * 512 + 256 + tid];
    }
#pragma unroll
    for (int r = 0; r < 16; ++r) {
      float4 xv = *(const float4*)&xs[r][k];
      acc0[r] = fmaf(xv.x, wa[0], acc0[r]);
      acc0[r] = fmaf(xv.y, wa[1], acc0[r]);
      acc0[r] = fmaf(xv.z, wa[2], acc0[r]);
      acc0[r] = fmaf(xv.w, wa[3], acc0[r]);
      acc1[r] = fmaf(xv.x, wb[0], acc1[r]);
      acc1[r] = fmaf(xv.y, wb[1], acc1[r]);
      acc1[r] = fmaf(xv.z, wb[2], acc1[r]);
      acc1[r] = fmaf(xv.w, wb[3], acc1[r]);
    }
  }
#pragma unroll
  for (int r = 0; r < 16; ++r) {
    out[(size_t)(row0 + r) * 512 + tid]       = acc0[r];
    out[(size_t)(row0 + r) * 512 + 256 + tid] = acc1[r];
  }
}

// ---------------- K1b: per-head softmax over 64, in place ----------------
__global__ __launch_bounds__(256) void k_softmax64(float* __restrict__ q,
                                                   float* __restrict__ k,
                                                   float* __restrict__ v) {
  int gw = (blockIdx.x * 256 + threadIdx.x) >> 6;
  int lane = threadIdx.x & 63;
  int arr = gw / (2048 * 8);
  int rem = gw - arr * (2048 * 8);
  float* p = (arr == 0) ? q : ((arr == 1) ? k : v);
  float* ptr = p + (size_t)rem * 64 + lane;
  float val = *ptr;
  float m = val;
#pragma unroll
  for (int off = 32; off; off >>= 1) m = fmaxf(m, __shfl_xor(m, off));
  float e = __expf((val - m) * INV_TAU);
  float s = e;
#pragma unroll
  for (int off = 32; off; off >>= 1) s += __shfl_xor(s, off);
  *ptr = e / s;
}

// ---------------- K2: causal QK^T into skewed layout ----------------
// S[bh][d][c] = sum_j q[bh][c+d][j] * k[bh][c][j],  valid iff d + c < T.
__global__ __launch_bounds__(256) void k_qkt(const float* __restrict__ q,
                                             const float* __restrict__ k,
                                             float* __restrict__ S) {
  int bh = blockIdx.x / 136;
  int tri = blockIdx.x - bh * 136;
  int di = 0;
  while (tri >= 16 - di) { tri -= 16 - di; ++di; }
  int cj = tri;
  int d0 = di * 64, c0 = cj * 64;
  int b = bh >> 3, h = bh & 7;

  __shared__ float ks[64][64];
  __shared__ float qs[128][64];
  int tid = threadIdx.x;

  for (int idx = tid; idx < 64 * 64; idx += 256) {
    int r = idx >> 6, j = idx & 63;
    ks[r][SW(r, j)] = k[((size_t)(b * TT + c0 + r) * HH + h) * 64 + j];
  }
  int tb = c0 + d0;
  for (int idx = tid; idx < 128 * 64; idx += 256) {
    int r = idx >> 6, j = idx & 63;
    int t = tb + r;
    qs[r][SW(r, j)] = (t < TT) ? q[((size_t)(b * TT + t) * HH + h) * 64 + j] : 0.0f;
  }
  __syncthreads();

  int tx = tid & 15, ty = tid >> 4;
  int cl = tx * 4, dl = ty * 4;
  int qbase = cl + dl;
  float acc[4][4] = {};
  for (int j = 0; j < 64; j += 4) {
    float kv[4][4], qv[7][4];
#pragma unroll
    for (int i = 0; i < 4; ++i) {
      float4 t4 = *(const float4*)&ks[cl + i][SW(cl + i, j)];
      kv[i][0] = t4.x; kv[i][1] = t4.y; kv[i][2] = t4.z; kv[i][3] = t4.w;
    }
#pragma unroll
    for (int i = 0; i < 7; ++i) {
      float4 t4 = *(const float4*)&qs[qbase + i][SW(qbase + i, j)];
      qv[i][0] = t4.x; qv[i][1] = t4.y; qv[i][2] = t4.z; qv[i][3] = t4.w;
    }
#pragma unroll
    for (int jj = 0; jj < 4; ++jj)
#pragma unroll
      for (int m = 0; m < 4; ++m)
#pragma unroll
        for (int i = 0; i < 4; ++i)
          acc[m][i] = fmaf(qv[m + i][jj], kv[i][jj], acc[m][i]);
  }

  float* Sb = S + (size_t)bh * TT * TT;
#pragma unroll
  for (int m = 0; m < 4; ++m) {
    int d = d0 + dl + m;
#pragma unroll
    for (int i = 0; i < 4; ++i) {
      int c = c0 + cl + i;
      if (d + c < TT) Sb[(size_t)d * TT + c] = acc[m][i];
    }
  }
}

// ---------------- K3: recurrence scan along skewed rows ----------------
// y[c] = x[c] * (y[c-1] + 1); linear form y = g*y_prev + a with g=a=x.
__global__ __launch_bounds__(256) void k_scan(float* __restrict__ S) {
  int gw = (blockIdx.x * 256 + threadIdx.x) >> 6;   // 0..16383
  int lane = threadIdx.x & 63;
  int bh = gw >> 10;
  int d = gw & 1023;
  float* row = S + (size_t)bh * TT * TT + (size_t)d * TT;
  int len = TT - d;
  float carry = 0.0f;
  for (int c0 = 0; c0 < len; c0 += 64) {
    int c = c0 + lane;
    bool act = (c < len);
    float xv = act ? row[c] : 0.0f;
    float G = xv, A = xv;
#pragma unroll
    for (int off = 1; off < 64; off <<= 1) {
      float gp = __shfl_up(G, off);
      float ap = __shfl_up(A, off);
      if (lane >= off) { A = fmaf(G, ap, A); G *= gp; }
    }
    float y = fmaf(G, carry, A);
    if (act) row[c] = y;
    carry = __shfl(y, 63);
  }
}

// ---------------- K4: fused softmax + PV + output projection ----------------
// block: (bh, 32-row t-tile), 4 waves, 8 t-rows per wave.
// Lane-parallel online softmax (lane = s), p written back into As row,
// PV with lane = channel reading p via broadcast float4.
__global__ __launch_bounds__(256) void k_attn(const float* __restrict__ S,
                                              const float* __restrict__ v,
                                              const float* __restrict__ wo,
                                              float* __restrict__ out) {
  int bh = blockIdx.x & 15;
  int ttile = 31 - (blockIdx.x >> 4);   // heavy tiles first
  int t0 = ttile * 32;
  int b = bh >> 3, h = bh & 7;

  __shared__ float As[32][64];
  __shared__ float vs[64][64];
  int tid = threadIdx.x;
  int wv = tid >> 6, lane = tid & 63;

  float o[8] = {};
  float lrun[8] = {};
  float mrun[8];
#pragma unroll
  for (int r = 0; r < 8; ++r) mrun[r] = -3e30f;

  const float* Sb = S + (size_t)bh * TT * TT;
  int nst = (t0 + 31) / 64 + 1;

  for (int st = 0; st < nst; ++st) {
    int s0 = st * 64;
    for (int idx = tid; idx < 64 * 64; idx += 256) {
      int sl = idx >> 6, e = idx & 63;
      vs[sl][e] = v[((size_t)(b * TT + s0 + sl) * HH + h) * 64 + e];
    }
    for (int idx = tid; idx < 32 * 64; idx += 256)
      (&As[0][0])[idx] = -1e30f;
    __syncthreads();
    // parallelogram gather: As[tl][s-s0] = S[t-s][s] for t=t0+tl
    int dbase = t0 - s0 - 63;
    for (int idx = tid; idx < 95 * 64; idx += 256) {
      int dd = idx >> 6, cl2 = idx & 63;
      int d = dbase + dd;
      if (d < 0) continue;
      int s = s0 + cl2;
      int tl = d + s - t0;
      if (tl < 0 || tl >= 32) continue;
      As[tl][cl2] = Sb[(size_t)d * TT + s];
    }
    __syncthreads();

#pragma unroll
    for (int r = 0; r < 8; ++r) {
      int tl = wv * 8 + r;
      int t = t0 + tl;
      if (s0 > t) continue;                 // wave-uniform
      float inv_t1 = 1.0f / (float)(t + 1);
      // lane-parallel: lane = s-local index
      float sc = As[tl][lane] + (float)(s0 + lane) * inv_t1;
      float mt = sc;
#pragma unroll
      for (int off = 32; off; off >>= 1) mt = fmaxf(mt, __shfl_xor(mt, off));
      float mnew = fmaxf(mrun[r], mt);
      float p = __expf((sc - mnew) * INV_TAU);   // masked lanes: p = 0
      float lsum = p;
#pragma unroll
      for (int off = 32; off; off >>= 1) lsum += __shfl_xor(lsum, off);
      float scale = __expf((mrun[r] - mnew) * INV_TAU);
      mrun[r] = mnew;
      o[r] *= scale;
      lrun[r] = lrun[r] * scale + lsum;
      As[tl][lane] = p;          // this wave's row only; same-wave LDS RAW
      // PV: lane = channel e; p read as uniform-address float4 (broadcast)
#pragma unroll
      for (int sl = 0; sl < 64; sl += 4) {
        float4 pv = *(const float4*)&As[tl][sl];
        o[r] = fmaf(pv.x, vs[sl + 0][lane], o[r]);
        o[r] = fmaf(pv.y, vs[sl + 1][lane], o[r]);
        o[r] = fmaf(pv.z, vs[sl + 2][lane], o[r]);
        o[r] = fmaf(pv.w, vs[sl + 3][lane], o[r]);
      }
    }
    __syncthreads();
  }

  // epilogue: normalize + per-head projection with wo[h][e][e']
#pragma unroll
  for (int r = 0; r < 8; ++r) {
    int t = t0 + wv * 8 + r;
    float on = o[r] / lrun[r];
    float res = 0.0f;
    for (int e = 0; e < 64; ++e) {
      float ov = __shfl(on, e);
      res = fmaf(ov, wo[(size_t)(h * 64 + e) * 64 + lane], res);
    }
    out[((size_t)(b * TT + t)) * 512 + h * 64 + lane] = res;
  }
}

extern "C" void kernel_launch(void* const* d_in, const int* in_sizes, int n_in,
                              void* d_out, int out_size, void* d_ws, size_t ws_size,
                              hipStream_t stream) {
  const float* x  = (const float*)d_in[0];
  const float* wq = (const float*)d_in[1];
  const float* wk = (const float*)d_in[2];
  const float* wv = (const float*)d_in[3];
  const float* wo = (const float*)d_in[4];
  float* out = (float*)d_out;

  char* ws = (char*)d_ws;
  const size_t MB = 1024 * 1024;
  float* q = (float*)(ws);              // 4 MB
  float* k = (float*)(ws + 4 * MB);     // 4 MB
  float* v = (float*)(ws + 8 * MB);     // 4 MB
  float* S = (float*)(ws + 12 * MB);    // 64 MB  (total 76 MB needed)

  // K1: projections (128 row-tiles x 3 matrices)
  k_proj<<<dim3(128, 3), 256, 0, stream>>>(x, wq, wk, wv, q, k, v);
  // K1b: per-head softmax in place (49152 waves)
  k_softmax64<<<12288, 256, 0, stream>>>(q, k, v);
  // K2: causal QK^T into skewed S (16 bh * 136 triangular tiles)
  k_qkt<<<BH * 136, 256, 0, stream>>>(q, k, S);
  // K3: diagonal recurrence scan (16*1024 rows, 4 waves/block)
  k_scan<<<4096, 256, 0, stream>>>(S);
  // K4: fused softmax + PV + output projection (16 bh * 32 t-tiles)
  k_attn<<<512, 256, 0, stream>>>(S, v, wo, out);
}

// Round 4
// 359.095 us; speedup vs baseline: 1.6638x; 1.6638x over previous
//
#include <hip/hip_runtime.h>
#include <hip/hip_bf16.h>
#include <math.h>

// ROSA QKV layer, fp32.
//  K1 k_proj      : q/k/v logits = x @ {wq,wk,wv}, 16 rows/block, k-unrolled x4
//  K1b k_softmax64: per-head softmax(logits/tau) over Hd=64, in place
//  K2 k_qkt       : causal QK^T directly into skewed coords S[d][c] = A[c+d][c]
//  K3 k_scan      : y[c] = x[c]*(y[c-1]+1) along skewed rows, wave shfl-scan
//  K4 k_attn_part : SPLIT-S flash partial: one block = (bh, 32-t-tile, one 64-s-chunk),
//                   gather skewed->normal tile, single-tile softmax + PV,
//                   write (m, l, o[64]) partials.  Perfect load balance, 4352 blocks.
//  K5 k_combine   : one wave per (bh,t): merge <=16 partials, normalize,
//                   per-head wo projection, write final output.
//
// ws layout: q 4MB | k 4MB | v 4MB | S 64MB | opart 64MB | mpart 1MB | lpart 1MB = 142MB

#define TT 1024
#define BB 2
#define HH 8
#define HD 64
#define DD 512
#define BH (BB*HH)

constexpr float INV_TAU = 10.0f;

// XOR swizzle for K2 fragment reads: bijective per row, float4-preserving.
#define SW(r, j) ((j) ^ ((((r) >> 2) & 7) << 2))

// ---------------- K1: projection GEMM (fp32) ----------------
__global__ __launch_bounds__(256) void k_proj(const float* __restrict__ x,
                                              const float* __restrict__ wq,
                                              const float* __restrict__ wk,
                                              const float* __restrict__ wv,
                                              float* __restrict__ oq,
                                              float* __restrict__ ok,
                                              float* __restrict__ ov) {
  __shared__ float xs[16][512];
  const int tid = threadIdx.x;
  const int arr = blockIdx.y;
  const float* __restrict__ W = (arr == 0) ? wq : ((arr == 1) ? wk : wv);
  float* __restrict__ out = (arr == 0) ? oq : ((arr == 1) ? ok : ov);
  const int row0 = blockIdx.x * 16;

  for (int idx = tid; idx < 16 * 512; idx += 256) {
    int r = idx >> 9, c = idx & 511;
    xs[r][c] = x[(size_t)(row0 + r) * 512 + c];
  }
  __syncthreads();

  float acc0[16] = {};
  float acc1[16] = {};
  for (int k = 0; k < 512; k += 4) {
    float wa[4], wb[4];
#pragma unroll
    for (int jj = 0; jj < 4; ++jj) {
      wa[jj] = W[(size_t)(k + jj) * 512 + tid];
      wb[jj] = W[(size_t)(k + jj) * 512 + 256 + tid];
    }
#pragma unroll
    for (int r = 0; r < 16; ++r) {
      float4 xv = *(const float4*)&xs[r][k];
      acc0[r] = fmaf(xv.x, wa[0], acc0[r]);
      acc0[r] = fmaf(xv.y, wa[1], acc0[r]);
      acc0[r] = fmaf(xv.z, wa[2], acc0[r]);
      acc0[r] = fmaf(xv.w, wa[3], acc0[r]);
      acc1[r] = fmaf(xv.x, wb[0], acc1[r]);
      acc1[r] = fmaf(xv.y, wb[1], acc1[r]);
      acc1[r] = fmaf(xv.z, wb[2], acc1[r]);
      acc1[r] = fmaf(xv.w, wb[3], acc1[r]);
    }
  }
#pragma unroll
  for (int r = 0; r < 16; ++r) {
    out[(size_t)(row0 + r) * 512 + tid]       = acc0[r];
    out[(size_t)(row0 + r) * 512 + 256 + tid] = acc1[r];
  }
}

// ---------------- K1b: per-head softmax over 64, in place ----------------
__global__ __launch_bounds__(256) void k_softmax64(float* __restrict__ q,
                                                   float* __restrict__ k,
                                                   float* __restrict__ v) {
  int gw = (blockIdx.x * 256 + threadIdx.x) >> 6;
  int lane = threadIdx.x & 63;
  int arr = gw / (2048 * 8);
  int rem = gw - arr * (2048 * 8);
  float* p = (arr == 0) ? q : ((arr == 1) ? k : v);
  float* ptr = p + (size_t)rem * 64 + lane;
  float val = *ptr;
  float m = val;
#pragma unroll
  for (int off = 32; off; off >>= 1) m = fmaxf(m, __shfl_xor(m, off));
  float e = __expf((val - m) * INV_TAU);
  float s = e;
#pragma unroll
  for (int off = 32; off; off >>= 1) s += __shfl_xor(s, off);
  *ptr = e / s;
}

// ---------------- K2: causal QK^T into skewed layout ----------------
// S[bh][d][c] = sum_j q[bh][c+d][j] * k[bh][c][j],  valid iff d + c < T.
__global__ __launch_bounds__(256) void k_qkt(const float* __restrict__ q,
                                             const float* __restrict__ k,
                                             float* __restrict__ S) {
  int bh = blockIdx.x / 136;
  int tri = blockIdx.x - bh * 136;
  int di = 0;
  while (tri >= 16 - di) { tri -= 16 - di; ++di; }
  int cj = tri;
  int d0 = di * 64, c0 = cj * 64;
  int b = bh >> 3, h = bh & 7;

  __shared__ float ks[64][64];
  __shared__ float qs[128][64];
  int tid = threadIdx.x;

  for (int idx = tid; idx < 64 * 64; idx += 256) {
    int r = idx >> 6, j = idx & 63;
    ks[r][SW(r, j)] = k[((size_t)(b * TT + c0 + r) * HH + h) * 64 + j];
  }
  int tb = c0 + d0;
  for (int idx = tid; idx < 128 * 64; idx += 256) {
    int r = idx >> 6, j = idx & 63;
    int t = tb + r;
    qs[r][SW(r, j)] = (t < TT) ? q[((size_t)(b * TT + t) * HH + h) * 64 + j] : 0.0f;
  }
  __syncthreads();

  int tx = tid & 15, ty = tid >> 4;
  int cl = tx * 4, dl = ty * 4;
  int qbase = cl + dl;
  float acc[4][4] = {};
  for (int j = 0; j < 64; j += 4) {
    float kv[4][4], qv[7][4];
#pragma unroll
    for (int i = 0; i < 4; ++i) {
      float4 t4 = *(const float4*)&ks[cl + i][SW(cl + i, j)];
      kv[i][0] = t4.x; kv[i][1] = t4.y; kv[i][2] = t4.z; kv[i][3] = t4.w;
    }
#pragma unroll
    for (int i = 0; i < 7; ++i) {
      float4 t4 = *(const float4*)&qs[qbase + i][SW(qbase + i, j)];
      qv[i][0] = t4.x; qv[i][1] = t4.y; qv[i][2] = t4.z; qv[i][3] = t4.w;
    }
#pragma unroll
    for (int jj = 0; jj < 4; ++jj)
#pragma unroll
      for (int m = 0; m < 4; ++m)
#pragma unroll
        for (int i = 0; i < 4; ++i)
          acc[m][i] = fmaf(qv[m + i][jj], kv[i][jj], acc[m][i]);
  }

  float* Sb = S + (size_t)bh * TT * TT;
#pragma unroll
  for (int m = 0; m < 4; ++m) {
    int d = d0 + dl + m;
#pragma unroll
    for (int i = 0; i < 4; ++i) {
      int c = c0 + cl + i;
      if (d + c < TT) Sb[(size_t)d * TT + c] = acc[m][i];
    }
  }
}

// ---------------- K3: recurrence scan along skewed rows ----------------
__global__ __launch_bounds__(256) void k_scan(float* __restrict__ S) {
  int gw = (blockIdx.x * 256 + threadIdx.x) >> 6;   // 0..16383
  int lane = threadIdx.x & 63;
  int bh = gw >> 10;
  int d = gw & 1023;
  float* row = S + (size_t)bh * TT * TT + (size_t)d * TT;
  int len = TT - d;
  float carry = 0.0f;
  for (int c0 = 0; c0 < len; c0 += 64) {
    int c = c0 + lane;
    bool act = (c < len);
    float xv = act ? row[c] : 0.0f;
    float G = xv, A = xv;
#pragma unroll
    for (int off = 1; off < 64; off <<= 1) {
      float gp = __shfl_up(G, off);
      float ap = __shfl_up(A, off);
      if (lane >= off) { A = fmaf(G, ap, A); G *= gp; }
    }
    float y = fmaf(G, carry, A);
    if (act) row[c] = y;
    carry = __shfl(y, 63);
  }
}

// ---------------- K4: split-s flash partial ----------------
// block = (bh, 32-row t-tile tt, s-chunk ci). 272 (tt,ci) pairs per bh.
// Computes single-tile softmax partials (m, l, o[64]) per active row.
__global__ __launch_bounds__(256) void k_attn_part(const float* __restrict__ S,
                                                   const float* __restrict__ v,
                                                   float* __restrict__ opart,
                                                   float* __restrict__ mpart,
                                                   float* __restrict__ lpart) {
  int bh = blockIdx.x / 272;
  int u = blockIdx.x - bh * 272;
  int tt = 0;
  while (true) { int nch = (tt + 2) >> 1; if (u < nch) break; u -= nch; ++tt; }
  int ci = u;
  int t0 = tt * 32, s0 = ci * 64;
  int b = bh >> 3, h = bh & 7;

  __shared__ float As[32][64];
  __shared__ float vs[64][64];
  int tid = threadIdx.x;
  int wv = tid >> 6, lane = tid & 63;

  for (int idx = tid; idx < 64 * 64; idx += 256) {
    int sl = idx >> 6, e = idx & 63;
    vs[sl][e] = v[((size_t)(b * TT + s0 + sl) * HH + h) * 64 + e];
  }
  for (int idx = tid; idx < 32 * 64; idx += 256)
    (&As[0][0])[idx] = -1e30f;
  __syncthreads();

  const float* Sb = S + (size_t)bh * TT * TT;
  int dbase = t0 - s0 - 63;
  for (int idx = tid; idx < 95 * 64; idx += 256) {
    int dd = idx >> 6, sl = idx & 63;
    int d = dbase + dd;
    if (d < 0) continue;
    int s = s0 + sl;
    int tl = d + s - t0;
    if (tl < 0 || tl >= 32) continue;
    As[tl][sl] = Sb[(size_t)d * TT + s];
  }
  __syncthreads();

#pragma unroll
  for (int r = 0; r < 8; ++r) {
    int tl = wv * 8 + r;
    int t = t0 + tl;
    if (t < s0) continue;               // wave-uniform: row fully masked
    float inv_t1 = 1.0f / (float)(t + 1);
    float sc = As[tl][lane] + (float)(s0 + lane) * inv_t1;
    float mt = sc;
#pragma unroll
    for (int off = 32; off; off >>= 1) mt = fmaxf(mt, __shfl_xor(mt, off));
    float p = __expf((sc - mt) * INV_TAU);     // masked lanes -> 0
    float lsum = p;
#pragma unroll
    for (int off = 32; off; off >>= 1) lsum += __shfl_xor(lsum, off);
    As[tl][lane] = p;                   // same-wave LDS round-trip
    float o = 0.0f;
#pragma unroll
    for (int sl = 0; sl < 64; sl += 4) {
      float4 pv = *(const float4*)&As[tl][sl];
      o = fmaf(pv.x, vs[sl + 0][lane], o);
      o = fmaf(pv.y, vs[sl + 1][lane], o);
      o = fmaf(pv.z, vs[sl + 2][lane], o);
      o = fmaf(pv.w, vs[sl + 3][lane], o);
    }
    size_t pidx = (size_t)(bh * TT + t) * 16 + ci;
    opart[pidx * 64 + lane] = o;
    if (lane == 0) { mpart[pidx] = mt; lpart[pidx] = lsum; }
  }
}

// ---------------- K5: combine partials + normalize + wo projection ----------------
// one wave per (bh, t); 4 rows (same bh/head) per block, wo[h] staged in LDS.
__global__ __launch_bounds__(256) void k_combine(const float* __restrict__ opart,
                                                 const float* __restrict__ mpart,
                                                 const float* __restrict__ lpart,
                                                 const float* __restrict__ wo,
                                                 float* __restrict__ out) {
  int bh = blockIdx.x >> 8;          // 16 bh x 256 t-groups
  int tg = blockIdx.x & 255;
  int b = bh >> 3, h = bh & 7;
  int tid = threadIdx.x;
  int wv = tid >> 6, lane = tid & 63;

  __shared__ float wos[64][64];
  for (int idx = tid; idx < 4096; idx += 256)
    (&wos[0][0])[idx] = wo[(size_t)h * 4096 + idx];
  __syncthreads();

  int t = tg * 4 + wv;
  int nc = (t >> 6) + 1;
  size_t base = (size_t)(bh * TT + t) * 16;

  float m = (lane < nc) ? mpart[base + lane] : -3e30f;
  float M = m;
#pragma unroll
  for (int off = 32; off; off >>= 1) M = fmaxf(M, __shfl_xor(M, off));
  float w = (lane < nc) ? __expf((m - M) * INV_TAU) : 0.0f;
  float lv = (lane < nc) ? lpart[base + lane] : 0.0f;
  float Lp = lv * w;
#pragma unroll
  for (int off = 32; off; off >>= 1) Lp += __shfl_xor(Lp, off);

  float o = 0.0f;
  for (int i = 0; i < nc; ++i) {
    float wi = __shfl(w, i);
    o = fmaf(wi, opart[(base + i) * 64 + lane], o);
  }
  float on = o / Lp;

  float res = 0.0f;
#pragma unroll 8
  for (int e = 0; e < 64; ++e)
    res = fmaf(__shfl(on, e), wos[e][lane], res);
  out[((size_t)(b * TT + t)) * 512 + h * 64 + lane] = res;
}

extern "C" void kernel_launch(void* const* d_in, const int* in_sizes, int n_in,
                              void* d_out, int out_size, void* d_ws, size_t ws_size,
                              hipStream_t stream) {
  const float* x  = (const float*)d_in[0];
  const float* wq = (const float*)d_in[1];
  const float* wk = (const float*)d_in[2];
  const float* wv = (const float*)d_in[3];
  const float* wo = (const float*)d_in[4];
  float* out = (float*)d_out;

  char* ws = (char*)d_ws;
  const size_t MB = 1024 * 1024;
  float* q     = (float*)(ws);               // 4 MB
  float* k     = (float*)(ws + 4 * MB);      // 4 MB
  float* v     = (float*)(ws + 8 * MB);      // 4 MB
  float* S     = (float*)(ws + 12 * MB);     // 64 MB
  float* opart = (float*)(ws + 76 * MB);     // 64 MB
  float* mpart = (float*)(ws + 140 * MB);    // 1 MB
  float* lpart = (float*)(ws + 141 * MB);    // 1 MB  (total 142 MB)

  // K1: projections (128 row-tiles x 3 matrices)
  k_proj<<<dim3(128, 3), 256, 0, stream>>>(x, wq, wk, wv, q, k, v);
  // K1b: per-head softmax in place
  k_softmax64<<<12288, 256, 0, stream>>>(q, k, v);
  // K2: causal QK^T into skewed S
  k_qkt<<<BH * 136, 256, 0, stream>>>(q, k, S);
  // K3: diagonal recurrence scan
  k_scan<<<4096, 256, 0, stream>>>(S);
  // K4: split-s flash partials (16 bh * 272 units, perfectly balanced)
  k_attn_part<<<BH * 272, 256, 0, stream>>>(S, v, opart, mpart, lpart);
  // K5: combine + normalize + output projection (16 bh * 256 row-groups)
  k_combine<<<4096, 256, 0, stream>>>(opart, mpart, lpart, wo, out);
}

// Round 6
// 328.900 us; speedup vs baseline: 1.8165x; 1.0918x over previous
//
#include <hip/hip_runtime.h>
#include <hip/hip_bf16.h>
#include <math.h>

// ROSA QKV layer, fp32.
//  K1 k_proj      : q/k/v = softmax_head((x @ W)/tau)  -- softmax FUSED into epilogue
//                   (wave w's 64 lanes = head w for acc0, head 4+w for acc1)
//  K2 k_qkt       : causal QK^T directly into skewed coords S[d][c] = A[c+d][c]
//  K3 k_scan      : y[c] = x[c]*(y[c-1]+1) along skewed rows, wave shfl-scan
//  K4 k_attn_part : split-s flash partial. PV restructured: s-quad outer with
//                   V cached in registers, rows inner via broadcast ds_read_b128
//                   (R4 counters: old version was LDS-pipe-bound on 512 b32/thread)
//  K5 k_combine   : one wave per (bh,t): merge <=16 partials, normalize,
//                   per-head wo projection, write final output.
//
// ws layout: q 4MB | k 4MB | v 4MB | S 64MB | opart 64MB | mpart 1MB | lpart 1MB = 142MB

#define TT 1024
#define BB 2
#define HH 8
#define HD 64
#define DD 512
#define BH (BB*HH)

constexpr float INV_TAU = 10.0f;

// XOR swizzle for K2 fragment reads: bijective per row, float4-preserving.
#define SW(r, j) ((j) ^ ((((r) >> 2) & 7) << 2))

// ---------------- K1: projection GEMM + fused per-head softmax ----------------
__global__ __launch_bounds__(256) void k_proj(const float* __restrict__ x,
                                              const float* __restrict__ wq,
                                              const float* __restrict__ wk,
                                              const float* __restrict__ wv,
                                              float* __restrict__ oq,
                                              float* __restrict__ ok,
                                              float* __restrict__ ov) {
  __shared__ float xs[16][512];
  const int tid = threadIdx.x;
  const int arr = blockIdx.y;
  const float* __restrict__ W = (arr == 0) ? wq : ((arr == 1) ? wk : wv);
  float* __restrict__ out = (arr == 0) ? oq : ((arr == 1) ? ok : ov);
  const int row0 = blockIdx.x * 16;

  for (int idx = tid; idx < 16 * 512; idx += 256) {
    int r = idx >> 9, c = idx & 511;
    xs[r][c] = x[(size_t)(row0 + r) * 512 + c];
  }
  __syncthreads();

  float acc0[16] = {};
  float acc1[16] = {};
  for (int k = 0; k < 512; k += 4) {
    float wa[4], wb[4];
#pragma unroll
    for (int jj = 0; jj < 4; ++jj) {
      wa[jj] = W[(size_t)(k + jj) * 512 + tid];
      wb[jj] = W[(size_t)(k + jj) * 512 + 256 + tid];
    }
#pragma unroll
    for (int r = 0; r < 16; ++r) {
      float4 xv = *(const float4*)&xs[r][k];
      acc0[r] = fmaf(xv.x, wa[0], acc0[r]);
      acc0[r] = fmaf(xv.y, wa[1], acc0[r]);
      acc0[r] = fmaf(xv.z, wa[2], acc0[r]);
      acc0[r] = fmaf(xv.w, wa[3], acc0[r]);
      acc1[r] = fmaf(xv.x, wb[0], acc1[r]);
      acc1[r] = fmaf(xv.y, wb[1], acc1[r]);
      acc1[r] = fmaf(xv.z, wb[2], acc1[r]);
      acc1[r] = fmaf(xv.w, wb[3], acc1[r]);
    }
  }
  // fused per-head softmax: wave covers cols [64w,64w+64) = head w (acc0)
  // and cols [256+64w, 256+64w+64) = head 4+w (acc1); pure wave reduction.
#pragma unroll
  for (int r = 0; r < 16; ++r) {
    float m0 = acc0[r], m1 = acc1[r];
#pragma unroll
    for (int off = 32; off; off >>= 1) {
      m0 = fmaxf(m0, __shfl_xor(m0, off));
      m1 = fmaxf(m1, __shfl_xor(m1, off));
    }
    float e0 = __expf((acc0[r] - m0) * INV_TAU);
    float e1 = __expf((acc1[r] - m1) * INV_TAU);
    float s0 = e0, s1 = e1;
#pragma unroll
    for (int off = 32; off; off >>= 1) {
      s0 += __shfl_xor(s0, off);
      s1 += __shfl_xor(s1, off);
    }
    out[(size_t)(row0 + r) * 512 + tid]       = e0 / s0;
    out[(size_t)(row0 + r) * 512 + 256 + tid] = e1 / s1;
  }
}

// ---------------- K2: causal QK^T into skewed layout ----------------
// S[bh][d][c] = sum_j q[bh][c+d][j] * k[bh][c][j],  valid iff d + c < T.
__global__ __launch_bounds__(256) void k_qkt(const float* __restrict__ q,
                                             const float* __restrict__ k,
                                             float* __restrict__ S) {
  int bh = blockIdx.x / 136;
  int tri = blockIdx.x - bh * 136;
  int di = 0;
  while (tri >= 16 - di) { tri -= 16 - di; ++di; }
  int cj = tri;
  int d0 = di * 64, c0 = cj * 64;
  int b = bh >> 3, h = bh & 7;

  __shared__ float ks[64][64];
  __shared__ float qs[128][64];
  int tid = threadIdx.x;

  for (int idx = tid; idx < 64 * 64; idx += 256) {
    int r = idx >> 6, j = idx & 63;
    ks[r][SW(r, j)] = k[((size_t)(b * TT + c0 + r) * HH + h) * 64 + j];
  }
  int tb = c0 + d0;
  for (int idx = tid; idx < 128 * 64; idx += 256) {
    int r = idx >> 6, j = idx & 63;
    int t = tb + r;
    qs[r][SW(r, j)] = (t < TT) ? q[((size_t)(b * TT + t) * HH + h) * 64 + j] : 0.0f;
  }
  __syncthreads();

  int tx = tid & 15, ty = tid >> 4;
  int cl = tx * 4, dl = ty * 4;
  int qbase = cl + dl;
  float acc[4][4] = {};
  for (int j = 0; j < 64; j += 4) {
    float kv[4][4], qv[7][4];
#pragma unroll
    for (int i = 0; i < 4; ++i) {
      float4 t4 = *(const float4*)&ks[cl + i][SW(cl + i, j)];
      kv[i][0] = t4.x; kv[i][1] = t4.y; kv[i][2] = t4.z; kv[i][3] = t4.w;
    }
#pragma unroll
    for (int i = 0; i < 7; ++i) {
      float4 t4 = *(const float4*)&qs[qbase + i][SW(qbase + i, j)];
      qv[i][0] = t4.x; qv[i][1] = t4.y; qv[i][2] = t4.z; qv[i][3] = t4.w;
    }
#pragma unroll
    for (int jj = 0; jj < 4; ++jj)
#pragma unroll
      for (int m = 0; m < 4; ++m)
#pragma unroll
        for (int i = 0; i < 4; ++i)
          acc[m][i] = fmaf(qv[m + i][jj], kv[i][jj], acc[m][i]);
  }

  float* Sb = S + (size_t)bh * TT * TT;
#pragma unroll
  for (int m = 0; m < 4; ++m) {
    int d = d0 + dl + m;
#pragma unroll
    for (int i = 0; i < 4; ++i) {
      int c = c0 + cl + i;
      if (d + c < TT) Sb[(size_t)d * TT + c] = acc[m][i];
    }
  }
}

// ---------------- K3: recurrence scan along skewed rows ----------------
__global__ __launch_bounds__(256) void k_scan(float* __restrict__ S) {
  int gw = (blockIdx.x * 256 + threadIdx.x) >> 6;   // 0..16383
  int lane = threadIdx.x & 63;
  int bh = gw >> 10;
  int d = gw & 1023;
  float* row = S + (size_t)bh * TT * TT + (size_t)d * TT;
  int len = TT - d;
  float carry = 0.0f;
  for (int c0 = 0; c0 < len; c0 += 64) {
    int c = c0 + lane;
    bool act = (c < len);
    float xv = act ? row[c] : 0.0f;
    float G = xv, A = xv;
#pragma unroll
    for (int off = 1; off < 64; off <<= 1) {
      float gp = __shfl_up(G, off);
      float ap = __shfl_up(A, off);
      if (lane >= off) { A = fmaf(G, ap, A); G *= gp; }
    }
    float y = fmaf(G, carry, A);
    if (act) row[c] = y;
    carry = __shfl(y, 63);
  }
}

// ---------------- K4: split-s flash partial (LDS-traffic-minimized) ----------------
// block = (bh, 32-row t-tile tt, s-chunk ci). All rows satisfy t >= s0 by construction.
__global__ __launch_bounds__(256) void k_attn_part(const float* __restrict__ S,
                                                   const float* __restrict__ v,
                                                   float* __restrict__ opart,
                                                   float* __restrict__ mpart,
                                                   float* __restrict__ lpart) {
  int bh = blockIdx.x / 272;
  int u = blockIdx.x - bh * 272;
  int tt = 0;
  while (true) { int nch = (tt + 2) >> 1; if (u < nch) break; u -= nch; ++tt; }
  int ci = u;
  int t0 = tt * 32, s0 = ci * 64;
  int b = bh >> 3, h = bh & 7;

  __shared__ float As[32][64];
  __shared__ float vs[64][64];
  int tid = threadIdx.x;
  int wv = tid >> 6, lane = tid & 63;

  // stage V with float4 (4 iterations)
  for (int idx = tid; idx < 64 * 16; idx += 256) {
    int sl = idx >> 4, e4 = (idx & 15) << 2;
    *(float4*)&vs[sl][e4] =
        *(const float4*)&v[((size_t)(b * TT + s0 + sl) * HH + h) * 64 + e4];
  }
  // parallelogram gather (diagonal-major: coalesced global reads)
  const float* Sb = S + (size_t)bh * TT * TT;
  int dbase = t0 - s0 - 63;
  for (int idx = tid; idx < 95 * 64; idx += 256) {
    int dd = idx >> 6, sl = idx & 63;
    int d = dbase + dd;
    if (d < 0) continue;
    int tl = d + sl + s0 - t0;
    if (tl < 0 || tl >= 32) continue;
    As[tl][sl] = Sb[(size_t)d * TT + s0 + sl];
  }
  __syncthreads();

  int tlb = wv * 8;
  // softmax per row (lane = s); masked lanes gated by predicate, p written to As
  for (int r = 0; r < 8; ++r) {
    int tl = tlb + r;
    int t = t0 + tl;
    float inv_t1 = 1.0f / (float)(t + 1);
    bool okl = (s0 + lane <= t);
    float sc = okl ? As[tl][lane] + (float)(s0 + lane) * inv_t1 : -1e30f;
    float mt = sc;
#pragma unroll
    for (int off = 32; off; off >>= 1) mt = fmaxf(mt, __shfl_xor(mt, off));
    float p = __expf((sc - mt) * INV_TAU);     // masked lanes -> 0
    float lsum = p;
#pragma unroll
    for (int off = 32; off; off >>= 1) lsum += __shfl_xor(lsum, off);
    As[tl][lane] = p;                          // covers all 64 lanes
    if (lane == 0) {
      size_t pidx = (size_t)(bh * TT + t) * 16 + ci;
      mpart[pidx] = mt; lpart[pidx] = lsum;
    }
  }
  // PV: s-quad outer, V cached in registers, rows inner via broadcast b128.
  // Reads only this wave's As rows -> same-wave ordering, no barrier needed.
  float o[8] = {};
  for (int sl = 0; sl < 64; sl += 4) {
    float v0 = vs[sl + 0][lane];
    float v1 = vs[sl + 1][lane];
    float v2 = vs[sl + 2][lane];
    float v3 = vs[sl + 3][lane];
#pragma unroll
    for (int r = 0; r < 8; ++r) {
      float4 pq = *(const float4*)&As[tlb + r][sl];
      o[r] = fmaf(pq.x, v0, o[r]);
      o[r] = fmaf(pq.y, v1, o[r]);
      o[r] = fmaf(pq.z, v2, o[r]);
      o[r] = fmaf(pq.w, v3, o[r]);
    }
  }
#pragma unroll
  for (int r = 0; r < 8; ++r) {
    int t = t0 + tlb + r;
    opart[((size_t)(bh * TT + t) * 16 + ci) * 64 + lane] = o[r];
  }
}

// ---------------- K5: combine partials + normalize + wo projection ----------------
__global__ __launch_bounds__(256) void k_combine(const float* __restrict__ opart,
                                                 const float* __restrict__ mpart,
                                                 const float* __restrict__ lpart,
                                                 const float* __restrict__ wo,
                                                 float* __restrict__ out) {
  int bh = blockIdx.x >> 8;          // 16 bh x 256 t-groups
  int tg = blockIdx.x & 255;
  int b = bh >> 3, h = bh & 7;
  int tid = threadIdx.x;
  int wv = tid >> 6, lane = tid & 63;

  __shared__ float wos[64][64];
  for (int idx = tid; idx < 4096; idx += 256)
    (&wos[0][0])[idx] = wo[(size_t)h * 4096 + idx];
  __syncthreads();

  int t = tg * 4 + wv;
  int nc = (t >> 6) + 1;
  size_t base = (size_t)(bh * TT + t) * 16;

  float m = (lane < nc) ? mpart[base + lane] : -3e30f;
  float M = m;
#pragma unroll
  for (int off = 32; off; off >>= 1) M = fmaxf(M, __shfl_xor(M, off));
  float w = (lane < nc) ? __expf((m - M) * INV_TAU) : 0.0f;
  float lv = (lane < nc) ? lpart[base + lane] : 0.0f;
  float Lp = lv * w;
#pragma unroll
  for (int off = 32; off; off >>= 1) Lp += __shfl_xor(Lp, off);

  float o = 0.0f;
  for (int i = 0; i < nc; ++i) {
    float wi = __shfl(w, i);
    o = fmaf(wi, opart[(base + i) * 64 + lane], o);
  }
  float on = o / Lp;

  float res = 0.0f;
#pragma unroll 8
  for (int e = 0; e < 64; ++e)
    res = fmaf(__shfl(on, e), wos[e][lane], res);
  out[((size_t)(b * TT + t)) * 512 + h * 64 + lane] = res;
}

extern "C" void kernel_launch(void* const* d_in, const int* in_sizes, int n_in,
                              void* d_out, int out_size, void* d_ws, size_t ws_size,
                              hipStream_t stream) {
  const float* x  = (const float*)d_in[0];
  const float* wq = (const float*)d_in[1];
  const float* wk = (const float*)d_in[2];
  const float* wv = (const float*)d_in[3];
  const float* wo = (const float*)d_in[4];
  float* out = (float*)d_out;

  char* ws = (char*)d_ws;
  const size_t MB = 1024 * 1024;
  float* q     = (float*)(ws);               // 4 MB
  float* k     = (float*)(ws + 4 * MB);      // 4 MB
  float* v     = (float*)(ws + 8 * MB);      // 4 MB
  float* S     = (float*)(ws + 12 * MB);     // 64 MB
  float* opart = (float*)(ws + 76 * MB);     // 64 MB
  float* mpart = (float*)(ws + 140 * MB);    // 1 MB
  float* lpart = (float*)(ws + 141 * MB);    // 1 MB  (total 142 MB)

  // K1: projections with fused per-head softmax
  k_proj<<<dim3(128, 3), 256, 0, stream>>>(x, wq, wk, wv, q, k, v);
  // K2: causal QK^T into skewed S
  k_qkt<<<BH * 136, 256, 0, stream>>>(q, k, S);
  // K3: diagonal recurrence scan
  k_scan<<<4096, 256, 0, stream>>>(S);
  // K4: split-s flash partials (16 bh * 272 units, perfectly balanced)
  k_attn_part<<<BH * 272, 256, 0, stream>>>(S, v, opart, mpart, lpart);
  // K5: combine + normalize + output projection (16 bh * 256 row-groups)
  k_combine<<<4096, 256, 0, stream>>>(opart, mpart, lpart, wo, out);
}

// Round 7
// 319.629 us; speedup vs baseline: 1.8692x; 1.0290x over previous
//
#include <hip/hip_runtime.h>
#include <hip/hip_bf16.h>
#include <math.h>

// ROSA QKV layer, fp32.
//  K1 k_proj      : q/k/v = softmax_head((x @ W)/tau), softmax fused.
//                   R6 rewrite: 8 rows/block (768 blocks = 3/CU), NO LDS —
//                   x read as wave-uniform float4 (scalar-pipe s_load), W as
//                   float2 per thread (cols 2t,2t+1). R6 counters showed the
//                   16-row LDS version was starved: 1.5 blocks/CU, occ 15.6%.
//  K2 k_qkt       : causal QK^T directly into skewed coords S[d][c] = A[c+d][c]
//  K3 k_scan      : y[c] = x[c]*(y[c-1]+1) along skewed rows, wave shfl-scan
//  K4 k_attn_part : split-s flash partial (PV: V-in-registers, broadcast b128)
//  K5 k_combine   : merge <=16 partials per row, normalize, wo projection.
//
// ws layout: q 4MB | k 4MB | v 4MB | S 64MB | opart 64MB | mpart 1MB | lpart 1MB = 142MB

#define TT 1024
#define BB 2
#define HH 8
#define HD 64
#define DD 512
#define BH (BB*HH)

constexpr float INV_TAU = 10.0f;

// XOR swizzle for K2 fragment reads: bijective per row, float4-preserving.
#define SW(r, j) ((j) ^ ((((r) >> 2) & 7) << 2))

// ---------------- K1: projection GEMM + fused per-head softmax ----------------
// 8 rows/block, thread t owns cols 2t and 2t+1. Head h = wave-half:
// wave w lanes 0-31 hold cols 128w..128w+63 (head 2w), lanes 32-63 head 2w+1.
__global__ __launch_bounds__(256) void k_proj(const float* __restrict__ x,
                                              const float* __restrict__ wq,
                                              const float* __restrict__ wk,
                                              const float* __restrict__ wv,
                                              float* __restrict__ oq,
                                              float* __restrict__ ok,
                                              float* __restrict__ ov) {
  const int tid = threadIdx.x;
  const int arr = blockIdx.y;
  const float* __restrict__ W = (arr == 0) ? wq : ((arr == 1) ? wk : wv);
  float* __restrict__ out = (arr == 0) ? oq : ((arr == 1) ? ok : ov);
  const int row0 = blockIdx.x * 8;
  const int c2 = tid * 2;

  float a0[8] = {};
  float a1[8] = {};
  for (int k = 0; k < 512; k += 4) {
    float2 w01[4];
#pragma unroll
    for (int jj = 0; jj < 4; ++jj)
      w01[jj] = *(const float2*)&W[(size_t)(k + jj) * 512 + c2];
#pragma unroll
    for (int r = 0; r < 8; ++r) {
      // wave-uniform address -> scalar load, broadcast to lanes
      float4 xv = *(const float4*)&x[(size_t)(row0 + r) * 512 + k];
      a0[r] = fmaf(xv.x, w01[0].x, a0[r]);
      a1[r] = fmaf(xv.x, w01[0].y, a1[r]);
      a0[r] = fmaf(xv.y, w01[1].x, a0[r]);
      a1[r] = fmaf(xv.y, w01[1].y, a1[r]);
      a0[r] = fmaf(xv.z, w01[2].x, a0[r]);
      a1[r] = fmaf(xv.z, w01[2].y, a1[r]);
      a0[r] = fmaf(xv.w, w01[3].x, a0[r]);
      a1[r] = fmaf(xv.w, w01[3].y, a1[r]);
    }
  }
  // fused per-head softmax: head spans a 32-lane half-wave x 2 col-slots;
  // shfl_xor with off<=16 stays within the half.
#pragma unroll
  for (int r = 0; r < 8; ++r) {
    float m01 = fmaxf(a0[r], a1[r]);
#pragma unroll
    for (int off = 16; off; off >>= 1) m01 = fmaxf(m01, __shfl_xor(m01, off));
    float e0 = __expf((a0[r] - m01) * INV_TAU);
    float e1 = __expf((a1[r] - m01) * INV_TAU);
    float s = e0 + e1;
#pragma unroll
    for (int off = 16; off; off >>= 1) s += __shfl_xor(s, off);
    float inv = 1.0f / s;
    *(float2*)&out[(size_t)(row0 + r) * 512 + c2] = make_float2(e0 * inv, e1 * inv);
  }
}

// ---------------- K2: causal QK^T into skewed layout ----------------
// S[bh][d][c] = sum_j q[bh][c+d][j] * k[bh][c][j],  valid iff d + c < T.
__global__ __launch_bounds__(256) void k_qkt(const float* __restrict__ q,
                                             const float* __restrict__ k,
                                             float* __restrict__ S) {
  int bh = blockIdx.x / 136;
  int tri = blockIdx.x - bh * 136;
  int di = 0;
  while (tri >= 16 - di) { tri -= 16 - di; ++di; }
  int cj = tri;
  int d0 = di * 64, c0 = cj * 64;
  int b = bh >> 3, h = bh & 7;

  __shared__ float ks[64][64];
  __shared__ float qs[128][64];
  int tid = threadIdx.x;

  for (int idx = tid; idx < 64 * 64; idx += 256) {
    int r = idx >> 6, j = idx & 63;
    ks[r][SW(r, j)] = k[((size_t)(b * TT + c0 + r) * HH + h) * 64 + j];
  }
  int tb = c0 + d0;
  for (int idx = tid; idx < 128 * 64; idx += 256) {
    int r = idx >> 6, j = idx & 63;
    int t = tb + r;
    qs[r][SW(r, j)] = (t < TT) ? q[((size_t)(b * TT + t) * HH + h) * 64 + j] : 0.0f;
  }
  __syncthreads();

  int tx = tid & 15, ty = tid >> 4;
  int cl = tx * 4, dl = ty * 4;
  int qbase = cl + dl;
  float acc[4][4] = {};
  for (int j = 0; j < 64; j += 4) {
    float kv[4][4], qv[7][4];
#pragma unroll
    for (int i = 0; i < 4; ++i) {
      float4 t4 = *(const float4*)&ks[cl + i][SW(cl + i, j)];
      kv[i][0] = t4.x; kv[i][1] = t4.y; kv[i][2] = t4.z; kv[i][3] = t4.w;
    }
#pragma unroll
    for (int i = 0; i < 7; ++i) {
      float4 t4 = *(const float4*)&qs[qbase + i][SW(qbase + i, j)];
      qv[i][0] = t4.x; qv[i][1] = t4.y; qv[i][2] = t4.z; qv[i][3] = t4.w;
    }
#pragma unroll
    for (int jj = 0; jj < 4; ++jj)
#pragma unroll
      for (int m = 0; m < 4; ++m)
#pragma unroll
        for (int i = 0; i < 4; ++i)
          acc[m][i] = fmaf(qv[m + i][jj], kv[i][jj], acc[m][i]);
  }

  float* Sb = S + (size_t)bh * TT * TT;
#pragma unroll
  for (int m = 0; m < 4; ++m) {
    int d = d0 + dl + m;
#pragma unroll
    for (int i = 0; i < 4; ++i) {
      int c = c0 + cl + i;
      if (d + c < TT) Sb[(size_t)d * TT + c] = acc[m][i];
    }
  }
}

// ---------------- K3: recurrence scan along skewed rows ----------------
__global__ __launch_bounds__(256) void k_scan(float* __restrict__ S) {
  int gw = (blockIdx.x * 256 + threadIdx.x) >> 6;   // 0..16383
  int lane = threadIdx.x & 63;
  int bh = gw >> 10;
  int d = gw & 1023;
  float* row = S + (size_t)bh * TT * TT + (size_t)d * TT;
  int len = TT - d;
  float carry = 0.0f;
  for (int c0 = 0; c0 < len; c0 += 64) {
    int c = c0 + lane;
    bool act = (c < len);
    float xv = act ? row[c] : 0.0f;
    float G = xv, A = xv;
#pragma unroll
    for (int off = 1; off < 64; off <<= 1) {
      float gp = __shfl_up(G, off);
      float ap = __shfl_up(A, off);
      if (lane >= off) { A = fmaf(G, ap, A); G *= gp; }
    }
    float y = fmaf(G, carry, A);
    if (act) row[c] = y;
    carry = __shfl(y, 63);
  }
}

// ---------------- K4: split-s flash partial (LDS-traffic-minimized) ----------------
// block = (bh, 32-row t-tile tt, s-chunk ci). All rows satisfy t >= s0 by construction.
__global__ __launch_bounds__(256) void k_attn_part(const float* __restrict__ S,
                                                   const float* __restrict__ v,
                                                   float* __restrict__ opart,
                                                   float* __restrict__ mpart,
                                                   float* __restrict__ lpart) {
  int bh = blockIdx.x / 272;
  int u = blockIdx.x - bh * 272;
  int tt = 0;
  while (true) { int nch = (tt + 2) >> 1; if (u < nch) break; u -= nch; ++tt; }
  int ci = u;
  int t0 = tt * 32, s0 = ci * 64;
  int b = bh >> 3, h = bh & 7;

  __shared__ float As[32][64];
  __shared__ float vs[64][64];
  int tid = threadIdx.x;
  int wv = tid >> 6, lane = tid & 63;

  // stage V with float4 (4 iterations)
  for (int idx = tid; idx < 64 * 16; idx += 256) {
    int sl = idx >> 4, e4 = (idx & 15) << 2;
    *(float4*)&vs[sl][e4] =
        *(const float4*)&v[((size_t)(b * TT + s0 + sl) * HH + h) * 64 + e4];
  }
  // parallelogram gather (diagonal-major: coalesced global reads)
  const float* Sb = S + (size_t)bh * TT * TT;
  int dbase = t0 - s0 - 63;
  for (int idx = tid; idx < 95 * 64; idx += 256) {
    int dd = idx >> 6, sl = idx & 63;
    int d = dbase + dd;
    if (d < 0) continue;
    int tl = d + sl + s0 - t0;
    if (tl < 0 || tl >= 32) continue;
    As[tl][sl] = Sb[(size_t)d * TT + s0 + sl];
  }
  __syncthreads();

  int tlb = wv * 8;
  // softmax per row (lane = s); masked lanes gated by predicate, p written to As
  for (int r = 0; r < 8; ++r) {
    int tl = tlb + r;
    int t = t0 + tl;
    float inv_t1 = 1.0f / (float)(t + 1);
    bool okl = (s0 + lane <= t);
    float sc = okl ? As[tl][lane] + (float)(s0 + lane) * inv_t1 : -1e30f;
    float mt = sc;
#pragma unroll
    for (int off = 32; off; off >>= 1) mt = fmaxf(mt, __shfl_xor(mt, off));
    float p = __expf((sc - mt) * INV_TAU);     // masked lanes -> 0
    float lsum = p;
#pragma unroll
    for (int off = 32; off; off >>= 1) lsum += __shfl_xor(lsum, off);
    As[tl][lane] = p;                          // covers all 64 lanes
    if (lane == 0) {
      size_t pidx = (size_t)(bh * TT + t) * 16 + ci;
      mpart[pidx] = mt; lpart[pidx] = lsum;
    }
  }
  // PV: s-quad outer, V cached in registers, rows inner via broadcast b128.
  // Reads only this wave's As rows -> same-wave ordering, no barrier needed.
  float o[8] = {};
  for (int sl = 0; sl < 64; sl += 4) {
    float v0 = vs[sl + 0][lane];
    float v1 = vs[sl + 1][lane];
    float v2 = vs[sl + 2][lane];
    float v3 = vs[sl + 3][lane];
#pragma unroll
    for (int r = 0; r < 8; ++r) {
      float4 pq = *(const float4*)&As[tlb + r][sl];
      o[r] = fmaf(pq.x, v0, o[r]);
      o[r] = fmaf(pq.y, v1, o[r]);
      o[r] = fmaf(pq.z, v2, o[r]);
      o[r] = fmaf(pq.w, v3, o[r]);
    }
  }
#pragma unroll
  for (int r = 0; r < 8; ++r) {
    int t = t0 + tlb + r;
    opart[((size_t)(bh * TT + t) * 16 + ci) * 64 + lane] = o[r];
  }
}

// ---------------- K5: combine partials + normalize + wo projection ----------------
__global__ __launch_bounds__(256) void k_combine(const float* __restrict__ opart,
                                                 const float* __restrict__ mpart,
                                                 const float* __restrict__ lpart,
                                                 const float* __restrict__ wo,
                                                 float* __restrict__ out) {
  int bh = blockIdx.x >> 8;          // 16 bh x 256 t-groups
  int tg = blockIdx.x & 255;
  int b = bh >> 3, h = bh & 7;
  int tid = threadIdx.x;
  int wv = tid >> 6, lane = tid & 63;

  __shared__ float wos[64][64];
  for (int idx = tid; idx < 4096; idx += 256)
    (&wos[0][0])[idx] = wo[(size_t)h * 4096 + idx];
  __syncthreads();

  int t = tg * 4 + wv;
  int nc = (t >> 6) + 1;
  size_t base = (size_t)(bh * TT + t) * 16;

  float m = (lane < nc) ? mpart[base + lane] : -3e30f;
  float M = m;
#pragma unroll
  for (int off = 32; off; off >>= 1) M = fmaxf(M, __shfl_xor(M, off));
  float w = (lane < nc) ? __expf((m - M) * INV_TAU) : 0.0f;
  float lv = (lane < nc) ? lpart[base + lane] : 0.0f;
  float Lp = lv * w;
#pragma unroll
  for (int off = 32; off; off >>= 1) Lp += __shfl_xor(Lp, off);

  float o = 0.0f;
  for (int i = 0; i < nc; ++i) {
    float wi = __shfl(w, i);
    o = fmaf(wi, opart[(base + i) * 64 + lane], o);
  }
  float on = o / Lp;

  float res = 0.0f;
#pragma unroll 8
  for (int e = 0; e < 64; ++e)
    res = fmaf(__shfl(on, e), wos[e][lane], res);
  out[((size_t)(b * TT + t)) * 512 + h * 64 + lane] = res;
}

extern "C" void kernel_launch(void* const* d_in, const int* in_sizes, int n_in,
                              void* d_out, int out_size, void* d_ws, size_t ws_size,
                              hipStream_t stream) {
  const float* x  = (const float*)d_in[0];
  const float* wq = (const float*)d_in[1];
  const float* wk = (const float*)d_in[2];
  const float* wv = (const float*)d_in[3];
  const float* wo = (const float*)d_in[4];
  float* out = (float*)d_out;

  char* ws = (char*)d_ws;
  const size_t MB = 1024 * 1024;
  float* q     = (float*)(ws);               // 4 MB
  float* k     = (float*)(ws + 4 * MB);      // 4 MB
  float* v     = (float*)(ws + 8 * MB);      // 4 MB
  float* S     = (float*)(ws + 12 * MB);     // 64 MB
  float* opart = (float*)(ws + 76 * MB);     // 64 MB
  float* mpart = (float*)(ws + 140 * MB);    // 1 MB
  float* lpart = (float*)(ws + 141 * MB);    // 1 MB  (total 142 MB)

  // K1: projections with fused per-head softmax (256 row-tiles x 3, 3 blocks/CU)
  k_proj<<<dim3(256, 3), 256, 0, stream>>>(x, wq, wk, wv, q, k, v);
  // K2: causal QK^T into skewed S
  k_qkt<<<BH * 136, 256, 0, stream>>>(q, k, S);
  // K3: diagonal recurrence scan
  k_scan<<<4096, 256, 0, stream>>>(S);
  // K4: split-s flash partials (16 bh * 272 units, perfectly balanced)
  k_attn_part<<<BH * 272, 256, 0, stream>>>(S, v, opart, mpart, lpart);
  // K5: combine + normalize + output projection (16 bh * 256 row-groups)
  k_combine<<<4096, 256, 0, stream>>>(opart, mpart, lpart, wo, out);
}

// Round 9
// 319.127 us; speedup vs baseline: 1.8721x; 1.0016x over previous
//
#include <hip/hip_runtime.h>
#include <hip/hip_bf16.h>
#include <math.h>

// ROSA QKV layer, fp32.
//  K1 k_proj      : q/k/v = softmax_head((x @ W)/tau), softmax fused.
//                   R7 rewrite: block = 8 rows x 256 cols (1 col/thread, acc[8]),
//                   grid 1536 = 6 blocks/CU, W k-unroll 8 with EXPLICIT double-
//                   buffer prefetch. R7 counters: prior version had VGPR=20 ->
//                   compiler serialized loads, 3 waves/SIMD couldn't hide L2 lat
//                   (VALUBusy 28%).
//  K2 k_qkt       : causal QK^T directly into skewed coords S[d][c] = A[c+d][c]
//  K3 k_scan      : y[c] = x[c]*(y[c-1]+1) along skewed rows, wave shfl-scan
//  K4 k_attn_part : split-s flash partial (PV: V-in-registers, broadcast b128)
//  K5 k_combine   : merge <=16 partials per row, normalize, wo projection.
//
// ws layout: q 4MB | k 4MB | v 4MB | S 64MB | opart 64MB | mpart 1MB | lpart 1MB = 142MB

#define TT 1024
#define BB 2
#define HH 8
#define HD 64
#define DD 512
#define BH (BB*HH)

constexpr float INV_TAU = 10.0f;

// XOR swizzle for K2 fragment reads: bijective per row, float4-preserving.
#define SW(r, j) ((j) ^ ((((r) >> 2) & 7) << 2))

// ---------------- K1: projection GEMM + fused per-head softmax ----------------
// block: 8 rows x 256 cols. blockIdx.x = row-tile*2 + col-half.
// thread t owns global col c = 256*ch + t; wave w == head 4*ch + w.
__global__ __launch_bounds__(256) void k_proj(const float* __restrict__ x,
                                              const float* __restrict__ wq,
                                              const float* __restrict__ wk,
                                              const float* __restrict__ wv,
                                              float* __restrict__ oq,
                                              float* __restrict__ ok,
                                              float* __restrict__ ov) {
  const int tid = threadIdx.x;
  const int arr = blockIdx.y;
  const float* __restrict__ W = (arr == 0) ? wq : ((arr == 1) ? wk : wv);
  float* __restrict__ out = (arr == 0) ? oq : ((arr == 1) ? ok : ov);
  const int row0 = (blockIdx.x >> 1) * 8;
  const int c = ((blockIdx.x & 1) << 8) + tid;

  float acc[8] = {};
  float wcur[8], wnxt[8];
#pragma unroll
  for (int j = 0; j < 8; ++j) wcur[j] = W[(size_t)j * 512 + c];

  for (int k = 0; k < 512; k += 8) {
    // prefetch next W chunk before consuming current (explicit SW pipeline)
    if (k + 8 < 512) {
#pragma unroll
      for (int j = 0; j < 8; ++j) wnxt[j] = W[(size_t)(k + 8 + j) * 512 + c];
    }
#pragma unroll
    for (int r = 0; r < 8; ++r) {
      // wave-uniform addresses -> scalar-pipe loads, broadcast to lanes
      float4 x0 = *(const float4*)&x[(size_t)(row0 + r) * 512 + k];
      float4 x1 = *(const float4*)&x[(size_t)(row0 + r) * 512 + k + 4];
      acc[r] = fmaf(x0.x, wcur[0], acc[r]);
      acc[r] = fmaf(x0.y, wcur[1], acc[r]);
      acc[r] = fmaf(x0.z, wcur[2], acc[r]);
      acc[r] = fmaf(x0.w, wcur[3], acc[r]);
      acc[r] = fmaf(x1.x, wcur[4], acc[r]);
      acc[r] = fmaf(x1.y, wcur[5], acc[r]);
      acc[r] = fmaf(x1.z, wcur[6], acc[r]);
      acc[r] = fmaf(x1.w, wcur[7], acc[r]);
    }
#pragma unroll
    for (int j = 0; j < 8; ++j) wcur[j] = wnxt[j];
  }

  // fused per-head softmax: wave = one head (64 lanes = 64 cols), full-wave reduce
#pragma unroll
  for (int r = 0; r < 8; ++r) {
    float m = acc[r];
#pragma unroll
    for (int off = 32; off; off >>= 1) m = fmaxf(m, __shfl_xor(m, off));
    float e = __expf((acc[r] - m) * INV_TAU);
    float s = e;
#pragma unroll
    for (int off = 32; off; off >>= 1) s += __shfl_xor(s, off);
    out[(size_t)(row0 + r) * 512 + c] = e / s;
  }
}

// ---------------- K2: causal QK^T into skewed layout ----------------
// S[bh][d][c] = sum_j q[bh][c+d][j] * k[bh][c][j],  valid iff d + c < T.
__global__ __launch_bounds__(256) void k_qkt(const float* __restrict__ q,
                                             const float* __restrict__ k,
                                             float* __restrict__ S) {
  int bh = blockIdx.x / 136;
  int tri = blockIdx.x - bh * 136;
  int di = 0;
  while (tri >= 16 - di) { tri -= 16 - di; ++di; }
  int cj = tri;
  int d0 = di * 64, c0 = cj * 64;
  int b = bh >> 3, h = bh & 7;

  __shared__ float ks[64][64];
  __shared__ float qs[128][64];
  int tid = threadIdx.x;

  for (int idx = tid; idx < 64 * 64; idx += 256) {
    int r = idx >> 6, j = idx & 63;
    ks[r][SW(r, j)] = k[((size_t)(b * TT + c0 + r) * HH + h) * 64 + j];
  }
  int tb = c0 + d0;
  for (int idx = tid; idx < 128 * 64; idx += 256) {
    int r = idx >> 6, j = idx & 63;
    int t = tb + r;
    qs[r][SW(r, j)] = (t < TT) ? q[((size_t)(b * TT + t) * HH + h) * 64 + j] : 0.0f;
  }
  __syncthreads();

  int tx = tid & 15, ty = tid >> 4;
  int cl = tx * 4, dl = ty * 4;
  int qbase = cl + dl;
  float acc[4][4] = {};
  for (int j = 0; j < 64; j += 4) {
    float kv[4][4], qv[7][4];
#pragma unroll
    for (int i = 0; i < 4; ++i) {
      float4 t4 = *(const float4*)&ks[cl + i][SW(cl + i, j)];
      kv[i][0] = t4.x; kv[i][1] = t4.y; kv[i][2] = t4.z; kv[i][3] = t4.w;
    }
#pragma unroll
    for (int i = 0; i < 7; ++i) {
      float4 t4 = *(const float4*)&qs[qbase + i][SW(qbase + i, j)];
      qv[i][0] = t4.x; qv[i][1] = t4.y; qv[i][2] = t4.z; qv[i][3] = t4.w;
    }
#pragma unroll
    for (int jj = 0; jj < 4; ++jj)
#pragma unroll
      for (int m = 0; m < 4; ++m)
#pragma unroll
        for (int i = 0; i < 4; ++i)
          acc[m][i] = fmaf(qv[m + i][jj], kv[i][jj], acc[m][i]);
  }

  float* Sb = S + (size_t)bh * TT * TT;
#pragma unroll
  for (int m = 0; m < 4; ++m) {
    int d = d0 + dl + m;
#pragma unroll
    for (int i = 0; i < 4; ++i) {
      int c = c0 + cl + i;
      if (d + c < TT) Sb[(size_t)d * TT + c] = acc[m][i];
    }
  }
}

// ---------------- K3: recurrence scan along skewed rows ----------------
__global__ __launch_bounds__(256) void k_scan(float* __restrict__ S) {
  int gw = (blockIdx.x * 256 + threadIdx.x) >> 6;   // 0..16383
  int lane = threadIdx.x & 63;
  int bh = gw >> 10;
  int d = gw & 1023;
  float* row = S + (size_t)bh * TT * TT + (size_t)d * TT;
  int len = TT - d;
  float carry = 0.0f;
  for (int c0 = 0; c0 < len; c0 += 64) {
    int c = c0 + lane;
    bool act = (c < len);
    float xv = act ? row[c] : 0.0f;
    float G = xv, A = xv;
#pragma unroll
    for (int off = 1; off < 64; off <<= 1) {
      float gp = __shfl_up(G, off);
      float ap = __shfl_up(A, off);
      if (lane >= off) { A = fmaf(G, ap, A); G *= gp; }
    }
    float y = fmaf(G, carry, A);
    if (act) row[c] = y;
    carry = __shfl(y, 63);
  }
}

// ---------------- K4: split-s flash partial (LDS-traffic-minimized) ----------------
// block = (bh, 32-row t-tile tt, s-chunk ci). All rows satisfy t >= s0 by construction.
__global__ __launch_bounds__(256) void k_attn_part(const float* __restrict__ S,
                                                   const float* __restrict__ v,
                                                   float* __restrict__ opart,
                                                   float* __restrict__ mpart,
                                                   float* __restrict__ lpart) {
  int bh = blockIdx.x / 272;
  int u = blockIdx.x - bh * 272;
  int tt = 0;
  while (true) { int nch = (tt + 2) >> 1; if (u < nch) break; u -= nch; ++tt; }
  int ci = u;
  int t0 = tt * 32, s0 = ci * 64;
  int b = bh >> 3, h = bh & 7;

  __shared__ float As[32][64];
  __shared__ float vs[64][64];
  int tid = threadIdx.x;
  int wv = tid >> 6, lane = tid & 63;

  // stage V with float4 (4 iterations)
  for (int idx = tid; idx < 64 * 16; idx += 256) {
    int sl = idx >> 4, e4 = (idx & 15) << 2;
    *(float4*)&vs[sl][e4] =
        *(const float4*)&v[((size_t)(b * TT + s0 + sl) * HH + h) * 64 + e4];
  }
  // parallelogram gather (diagonal-major: coalesced global reads)
  const float* Sb = S + (size_t)bh * TT * TT;
  int dbase = t0 - s0 - 63;
  for (int idx = tid; idx < 95 * 64; idx += 256) {
    int dd = idx >> 6, sl = idx & 63;
    int d = dbase + dd;
    if (d < 0) continue;
    int tl = d + sl + s0 - t0;
    if (tl < 0 || tl >= 32) continue;
    As[tl][sl] = Sb[(size_t)d * TT + s0 + sl];
  }
  __syncthreads();

  int tlb = wv * 8;
  // softmax per row (lane = s); masked lanes gated by predicate, p written to As
  for (int r = 0; r < 8; ++r) {
    int tl = tlb + r;
    int t = t0 + tl;
    float inv_t1 = 1.0f / (float)(t + 1);
    bool okl = (s0 + lane <= t);
    float sc = okl ? As[tl][lane] + (float)(s0 + lane) * inv_t1 : -1e30f;
    float mt = sc;
#pragma unroll
    for (int off = 32; off; off >>= 1) mt = fmaxf(mt, __shfl_xor(mt, off));
    float p = __expf((sc - mt) * INV_TAU);     // masked lanes -> 0
    float lsum = p;
#pragma unroll
    for (int off = 32; off; off >>= 1) lsum += __shfl_xor(lsum, off);
    As[tl][lane] = p;                          // covers all 64 lanes
    if (lane == 0) {
      size_t pidx = (size_t)(bh * TT + t) * 16 + ci;
      mpart[pidx] = mt; lpart[pidx] = lsum;
    }
  }
  // PV: s-quad outer, V cached in registers, rows inner via broadcast b128.
  // Reads only this wave's As rows -> same-wave ordering, no barrier needed.
  float o[8] = {};
  for (int sl = 0; sl < 64; sl += 4) {
    float v0 = vs[sl + 0][lane];
    float v1 = vs[sl + 1][lane];
    float v2 = vs[sl + 2][lane];
    float v3 = vs[sl + 3][lane];
#pragma unroll
    for (int r = 0; r < 8; ++r) {
      float4 pq = *(const float4*)&As[tlb + r][sl];
      o[r] = fmaf(pq.x, v0, o[r]);
      o[r] = fmaf(pq.y, v1, o[r]);
      o[r] = fmaf(pq.z, v2, o[r]);
      o[r] = fmaf(pq.w, v3, o[r]);
    }
  }
#pragma unroll
  for (int r = 0; r < 8; ++r) {
    int t = t0 + tlb + r;
    opart[((size_t)(bh * TT + t) * 16 + ci) * 64 + lane] = o[r];
  }
}

// ---------------- K5: combine partials + normalize + wo projection ----------------
__global__ __launch_bounds__(256) void k_combine(const float* __restrict__ opart,
                                                 const float* __restrict__ mpart,
                                                 const float* __restrict__ lpart,
                                                 const float* __restrict__ wo,
                                                 float* __restrict__ out) {
  int bh = blockIdx.x >> 8;          // 16 bh x 256 t-groups
  int tg = blockIdx.x & 255;
  int b = bh >> 3, h = bh & 7;
  int tid = threadIdx.x;
  int wv = tid >> 6, lane = tid & 63;

  __shared__ float wos[64][64];
  for (int idx = tid; idx < 4096; idx += 256)
    (&wos[0][0])[idx] = wo[(size_t)h * 4096 + idx];
  __syncthreads();

  int t = tg * 4 + wv;
  int nc = (t >> 6) + 1;
  size_t base = (size_t)(bh * TT + t) * 16;

  float m = (lane < nc) ? mpart[base + lane] : -3e30f;
  float M = m;
#pragma unroll
  for (int off = 32; off; off >>= 1) M = fmaxf(M, __shfl_xor(M, off));
  float w = (lane < nc) ? __expf((m - M) * INV_TAU) : 0.0f;
  float lv = (lane < nc) ? lpart[base + lane] : 0.0f;
  float Lp = lv * w;
#pragma unroll
  for (int off = 32; off; off >>= 1) Lp += __shfl_xor(Lp, off);

  float o = 0.0f;
  for (int i = 0; i < nc; ++i) {
    float wi = __shfl(w, i);
    o = fmaf(wi, opart[(base + i) * 64 + lane], o);
  }
  float on = o / Lp;

  float res = 0.0f;
#pragma unroll 8
  for (int e = 0; e < 64; ++e)
    res = fmaf(__shfl(on, e), wos[e][lane], res);
  out[((size_t)(b * TT + t)) * 512 + h * 64 + lane] = res;
}

extern "C" void kernel_launch(void* const* d_in, const int* in_sizes, int n_in,
                              void* d_out, int out_size, void* d_ws, size_t ws_size,
                              hipStream_t stream) {
  const float* x  = (const float*)d_in[0];
  const float* wq = (const float*)d_in[1];
  const float* wk = (const float*)d_in[2];
  const float* wv = (const float*)d_in[3];
  const float* wo = (const float*)d_in[4];
  float* out = (float*)d_out;

  char* ws = (char*)d_ws;
  const size_t MB = 1024 * 1024;
  float* q     = (float*)(ws);               // 4 MB
  float* k     = (float*)(ws + 4 * MB);      // 4 MB
  float* v     = (float*)(ws + 8 * MB);      // 4 MB
  float* S     = (float*)(ws + 12 * MB);     // 64 MB
  float* opart = (float*)(ws + 76 * MB);     // 64 MB
  float* mpart = (float*)(ws + 140 * MB);    // 1 MB
  float* lpart = (float*)(ws + 141 * MB);    // 1 MB  (total 142 MB)

  // K1: projections (256 row-tiles x 2 col-halves x 3 mats = 1536 blocks, 6/CU)
  k_proj<<<dim3(512, 3), 256, 0, stream>>>(x, wq, wk, wv, q, k, v);
  // K2: causal QK^T into skewed S
  k_qkt<<<BH * 136, 256, 0, stream>>>(q, k, S);
  // K3: diagonal recurrence scan
  k_scan<<<4096, 256, 0, stream>>>(S);
  // K4: split-s flash partials (16 bh * 272 units, perfectly balanced)
  k_attn_part<<<BH * 272, 256, 0, stream>>>(S, v, opart, mpart, lpart);
  // K5: combine + normalize + output projection (16 bh * 256 row-groups)
  k_combine<<<4096, 256, 0, stream>>>(opart, mpart, lpart, wo, out);
}

// Round 13
// 309.254 us; speedup vs baseline: 1.9319x; 1.0319x over previous
//
#include <hip/hip_runtime.h>
#include <hip/hip_bf16.h>
#include <math.h>

// ROSA QKV layer, fp32.
//  K1 k_proj      : q/k/v = softmax_head((x @ W)/tau), softmax fused.
//                   R9 rewrite: x staged in LDS (16KB), k-loop reads x via
//                   uniform-address ds_read_b128 (broadcast, in-order counter ->
//                   compiler can pipeline). R9 counters proved the prior version
//                   serialized on out-of-order s_load x reads (SGPR=80,
//                   lgkmcnt(0) per iter, VALUBusy 40% at 55% occupancy).
//                   Block = 8 rows x 512 cols, 2 cols/thread, grid 768 = 3/CU.
//  K2 k_qkt       : causal QK^T directly into skewed coords S[d][c] = A[c+d][c]
//  K3 k_scan      : y[c] = x[c]*(y[c-1]+1) along skewed rows, wave shfl-scan
//  K4 k_attn_part : split-s flash partial (PV: V-in-registers, broadcast b128)
//  K5 k_combine   : merge <=16 partials per row, normalize, wo projection.
//
// ws layout: q 4MB | k 4MB | v 4MB | S 64MB | opart 64MB | mpart 1MB | lpart 1MB = 142MB

#define TT 1024
#define BB 2
#define HH 8
#define HD 64
#define DD 512
#define BH (BB*HH)

constexpr float INV_TAU = 10.0f;

// XOR swizzle for K2 fragment reads: bijective per row, float4-preserving.
#define SW(r, j) ((j) ^ ((((r) >> 2) & 7) << 2))

// ---------------- K1: projection GEMM + fused per-head softmax ----------------
// block: 8 rows x 512 cols, thread t owns cols 2t,2t+1. Wave w covers cols
// [128w,128w+128) = heads 2w (lanes 0-31) and 2w+1 (lanes 32-63); half-wave
// shfl_xor (off<=16) reduces exactly within one head.
__global__ __launch_bounds__(256) void k_proj(const float* __restrict__ x,
                                              const float* __restrict__ wq,
                                              const float* __restrict__ wk,
                                              const float* __restrict__ wv,
                                              float* __restrict__ oq,
                                              float* __restrict__ ok,
                                              float* __restrict__ ov) {
  __shared__ float xs[8 * 512];
  const int tid = threadIdx.x;
  const int arr = blockIdx.y;
  const float* __restrict__ W = (arr == 0) ? wq : ((arr == 1) ? wk : wv);
  float* __restrict__ out = (arr == 0) ? oq : ((arr == 1) ? ok : ov);
  const int row0 = blockIdx.x * 8;
  const int c2 = tid * 2;

  // stage x: the 8 rows are one contiguous 4096-float span of x
  const float* __restrict__ xb = &x[(size_t)row0 * 512];
#pragma unroll
  for (int i = 0; i < 4; ++i) {
    int idx = (i * 256 + tid) * 4;
    *(float4*)&xs[idx] = *(const float4*)&xb[idx];
  }
  __syncthreads();

  float acc0[8] = {};
  float acc1[8] = {};
  float2 wcur[8], wnxt[8];
#pragma unroll
  for (int j = 0; j < 8; ++j) wcur[j] = *(const float2*)&W[(size_t)j * 512 + c2];

  for (int k = 0; k < 512; k += 8) {
    // prefetch next W chunk (explicit SW pipeline on the VMEM path)
    if (k + 8 < 512) {
#pragma unroll
      for (int j = 0; j < 8; ++j)
        wnxt[j] = *(const float2*)&W[(size_t)(k + 8 + j) * 512 + c2];
    }
#pragma unroll
    for (int r = 0; r < 8; ++r) {
      // uniform-address LDS reads: broadcast, in-order lgkmcnt -> pipelined
      float4 x0 = *(const float4*)&xs[r * 512 + k];
      float4 x1 = *(const float4*)&xs[r * 512 + k + 4];
      acc0[r] = fmaf(x0.x, wcur[0].x, acc0[r]);
      acc1[r] = fmaf(x0.x, wcur[0].y, acc1[r]);
      acc0[r] = fmaf(x0.y, wcur[1].x, acc0[r]);
      acc1[r] = fmaf(x0.y, wcur[1].y, acc1[r]);
      acc0[r] = fmaf(x0.z, wcur[2].x, acc0[r]);
      acc1[r] = fmaf(x0.z, wcur[2].y, acc1[r]);
      acc0[r] = fmaf(x0.w, wcur[3].x, acc0[r]);
      acc1[r] = fmaf(x0.w, wcur[3].y, acc1[r]);
      acc0[r] = fmaf(x1.x, wcur[4].x, acc0[r]);
      acc1[r] = fmaf(x1.x, wcur[4].y, acc1[r]);
      acc0[r] = fmaf(x1.y, wcur[5].x, acc0[r]);
      acc1[r] = fmaf(x1.y, wcur[5].y, acc1[r]);
      acc0[r] = fmaf(x1.z, wcur[6].x, acc0[r]);
      acc1[r] = fmaf(x1.z, wcur[6].y, acc1[r]);
      acc0[r] = fmaf(x1.w, wcur[7].x, acc0[r]);
      acc1[r] = fmaf(x1.w, wcur[7].y, acc1[r]);
    }
#pragma unroll
    for (int j = 0; j < 8; ++j) wcur[j] = wnxt[j];
  }

  // fused per-head softmax: half-wave = one head (32 lanes x 2 cols)
#pragma unroll
  for (int r = 0; r < 8; ++r) {
    float m = fmaxf(acc0[r], acc1[r]);
#pragma unroll
    for (int off = 16; off; off >>= 1) m = fmaxf(m, __shfl_xor(m, off));
    float e0 = __expf((acc0[r] - m) * INV_TAU);
    float e1 = __expf((acc1[r] - m) * INV_TAU);
    float s = e0 + e1;
#pragma unroll
    for (int off = 16; off; off >>= 1) s += __shfl_xor(s, off);
    float inv = 1.0f / s;
    *(float2*)&out[(size_t)(row0 + r) * 512 + c2] = make_float2(e0 * inv, e1 * inv);
  }
}

// ---------------- K2: causal QK^T into skewed layout ----------------
// S[bh][d][c] = sum_j q[bh][c+d][j] * k[bh][c][j],  valid iff d + c < T.
__global__ __launch_bounds__(256) void k_qkt(const float* __restrict__ q,
                                             const float* __restrict__ k,
                                             float* __restrict__ S) {
  int bh = blockIdx.x / 136;
  int tri = blockIdx.x - bh * 136;
  int di = 0;
  while (tri >= 16 - di) { tri -= 16 - di; ++di; }
  int cj = tri;
  int d0 = di * 64, c0 = cj * 64;
  int b = bh >> 3, h = bh & 7;

  __shared__ float ks[64][64];
  __shared__ float qs[128][64];
  int tid = threadIdx.x;

  for (int idx = tid; idx < 64 * 64; idx += 256) {
    int r = idx >> 6, j = idx & 63;
    ks[r][SW(r, j)] = k[((size_t)(b * TT + c0 + r) * HH + h) * 64 + j];
  }
  int tb = c0 + d0;
  for (int idx = tid; idx < 128 * 64; idx += 256) {
    int r = idx >> 6, j = idx & 63;
    int t = tb + r;
    qs[r][SW(r, j)] = (t < TT) ? q[((size_t)(b * TT + t) * HH + h) * 64 + j] : 0.0f;
  }
  __syncthreads();

  int tx = tid & 15, ty = tid >> 4;
  int cl = tx * 4, dl = ty * 4;
  int qbase = cl + dl;
  float acc[4][4] = {};
  for (int j = 0; j < 64; j += 4) {
    float kv[4][4], qv[7][4];
#pragma unroll
    for (int i = 0; i < 4; ++i) {
      float4 t4 = *(const float4*)&ks[cl + i][SW(cl + i, j)];
      kv[i][0] = t4.x; kv[i][1] = t4.y; kv[i][2] = t4.z; kv[i][3] = t4.w;
    }
#pragma unroll
    for (int i = 0; i < 7; ++i) {
      float4 t4 = *(const float4*)&qs[qbase + i][SW(qbase + i, j)];
      qv[i][0] = t4.x; qv[i][1] = t4.y; qv[i][2] = t4.z; qv[i][3] = t4.w;
    }
#pragma unroll
    for (int jj = 0; jj < 4; ++jj)
#pragma unroll
      for (int m = 0; m < 4; ++m)
#pragma unroll
        for (int i = 0; i < 4; ++i)
          acc[m][i] = fmaf(qv[m + i][jj], kv[i][jj], acc[m][i]);
  }

  float* Sb = S + (size_t)bh * TT * TT;
#pragma unroll
  for (int m = 0; m < 4; ++m) {
    int d = d0 + dl + m;
#pragma unroll
    for (int i = 0; i < 4; ++i) {
      int c = c0 + cl + i;
      if (d + c < TT) Sb[(size_t)d * TT + c] = acc[m][i];
    }
  }
}

// ---------------- K3: recurrence scan along skewed rows ----------------
__global__ __launch_bounds__(256) void k_scan(float* __restrict__ S) {
  int gw = (blockIdx.x * 256 + threadIdx.x) >> 6;   // 0..16383
  int lane = threadIdx.x & 63;
  int bh = gw >> 10;
  int d = gw & 1023;
  float* row = S + (size_t)bh * TT * TT + (size_t)d * TT;
  int len = TT - d;
  float carry = 0.0f;
  for (int c0 = 0; c0 < len; c0 += 64) {
    int c = c0 + lane;
    bool act = (c < len);
    float xv = act ? row[c] : 0.0f;
    float G = xv, A = xv;
#pragma unroll
    for (int off = 1; off < 64; off <<= 1) {
      float gp = __shfl_up(G, off);
      float ap = __shfl_up(A, off);
      if (lane >= off) { A = fmaf(G, ap, A); G *= gp; }
    }
    float y = fmaf(G, carry, A);
    if (act) row[c] = y;
    carry = __shfl(y, 63);
  }
}

// ---------------- K4: split-s flash partial (LDS-traffic-minimized) ----------------
// block = (bh, 32-row t-tile tt, s-chunk ci). All rows satisfy t >= s0 by construction.
__global__ __launch_bounds__(256) void k_attn_part(const float* __restrict__ S,
                                                   const float* __restrict__ v,
                                                   float* __restrict__ opart,
                                                   float* __restrict__ mpart,
                                                   float* __restrict__ lpart) {
  int bh = blockIdx.x / 272;
  int u = blockIdx.x - bh * 272;
  int tt = 0;
  while (true) { int nch = (tt + 2) >> 1; if (u < nch) break; u -= nch; ++tt; }
  int ci = u;
  int t0 = tt * 32, s0 = ci * 64;
  int b = bh >> 3, h = bh & 7;

  __shared__ float As[32][64];
  __shared__ float vs[64][64];
  int tid = threadIdx.x;
  int wv = tid >> 6, lane = tid & 63;

  // stage V with float4 (4 iterations)
  for (int idx = tid; idx < 64 * 16; idx += 256) {
    int sl = idx >> 4, e4 = (idx & 15) << 2;
    *(float4*)&vs[sl][e4] =
        *(const float4*)&v[((size_t)(b * TT + s0 + sl) * HH + h) * 64 + e4];
  }
  // parallelogram gather (diagonal-major: coalesced global reads)
  const float* Sb = S + (size_t)bh * TT * TT;
  int dbase = t0 - s0 - 63;
  for (int idx = tid; idx < 95 * 64; idx += 256) {
    int dd = idx >> 6, sl = idx & 63;
    int d = dbase + dd;
    if (d < 0) continue;
    int tl = d + sl + s0 - t0;
    if (tl < 0 || tl >= 32) continue;
    As[tl][sl] = Sb[(size_t)d * TT + s0 + sl];
  }
  __syncthreads();

  int tlb = wv * 8;
  // softmax per row (lane = s); masked lanes gated by predicate, p written to As
  for (int r = 0; r < 8; ++r) {
    int tl = tlb + r;
    int t = t0 + tl;
    float inv_t1 = 1.0f / (float)(t + 1);
    bool okl = (s0 + lane <= t);
    float sc = okl ? As[tl][lane] + (float)(s0 + lane) * inv_t1 : -1e30f;
    float mt = sc;
#pragma unroll
    for (int off = 32; off; off >>= 1) mt = fmaxf(mt, __shfl_xor(mt, off));
    float p = __expf((sc - mt) * INV_TAU);     // masked lanes -> 0
    float lsum = p;
#pragma unroll
    for (int off = 32; off; off >>= 1) lsum += __shfl_xor(lsum, off);
    As[tl][lane] = p;                          // covers all 64 lanes
    if (lane == 0) {
      size_t pidx = (size_t)(bh * TT + t) * 16 + ci;
      mpart[pidx] = mt; lpart[pidx] = lsum;
    }
  }
  // PV: s-quad outer, V cached in registers, rows inner via broadcast b128.
  // Reads only this wave's As rows -> same-wave ordering, no barrier needed.
  float o[8] = {};
  for (int sl = 0; sl < 64; sl += 4) {
    float v0 = vs[sl + 0][lane];
    float v1 = vs[sl + 1][lane];
    float v2 = vs[sl + 2][lane];
    float v3 = vs[sl + 3][lane];
#pragma unroll
    for (int r = 0; r < 8; ++r) {
      float4 pq = *(const float4*)&As[tlb + r][sl];
      o[r] = fmaf(pq.x, v0, o[r]);
      o[r] = fmaf(pq.y, v1, o[r]);
      o[r] = fmaf(pq.z, v2, o[r]);
      o[r] = fmaf(pq.w, v3, o[r]);
    }
  }
#pragma unroll
  for (int r = 0; r < 8; ++r) {
    int t = t0 + tlb + r;
    opart[((size_t)(bh * TT + t) * 16 + ci) * 64 + lane] = o[r];
  }
}

// ---------------- K5: combine partials + normalize + wo projection ----------------
__global__ __launch_bounds__(256) void k_combine(const float* __restrict__ opart,
                                                 const float* __restrict__ mpart,
                                                 const float* __restrict__ lpart,
                                                 const float* __restrict__ wo,
                                                 float* __restrict__ out) {
  int bh = blockIdx.x >> 8;          // 16 bh x 256 t-groups
  int tg = blockIdx.x & 255;
  int b = bh >> 3, h = bh & 7;
  int tid = threadIdx.x;
  int wv = tid >> 6, lane = tid & 63;

  __shared__ float wos[64][64];
  for (int idx = tid; idx < 4096; idx += 256)
    (&wos[0][0])[idx] = wo[(size_t)h * 4096 + idx];
  __syncthreads();

  int t = tg * 4 + wv;
  int nc = (t >> 6) + 1;
  size_t base = (size_t)(bh * TT + t) * 16;

  float m = (lane < nc) ? mpart[base + lane] : -3e30f;
  float M = m;
#pragma unroll
  for (int off = 32; off; off >>= 1) M = fmaxf(M, __shfl_xor(M, off));
  float w = (lane < nc) ? __expf((m - M) * INV_TAU) : 0.0f;
  float lv = (lane < nc) ? lpart[base + lane] : 0.0f;
  float Lp = lv * w;
#pragma unroll
  for (int off = 32; off; off >>= 1) Lp += __shfl_xor(Lp, off);

  float o = 0.0f;
  for (int i = 0; i < nc; ++i) {
    float wi = __shfl(w, i);
    o = fmaf(wi, opart[(base + i) * 64 + lane], o);
  }
  float on = o / Lp;

  float res = 0.0f;
#pragma unroll 8
  for (int e = 0; e < 64; ++e)
    res = fmaf(__shfl(on, e), wos[e][lane], res);
  out[((size_t)(b * TT + t)) * 512 + h * 64 + lane] = res;
}

extern "C" void kernel_launch(void* const* d_in, const int* in_sizes, int n_in,
                              void* d_out, int out_size, void* d_ws, size_t ws_size,
                              hipStream_t stream) {
  const float* x  = (const float*)d_in[0];
  const float* wq = (const float*)d_in[1];
  const float* wk = (const float*)d_in[2];
  const float* wv = (const float*)d_in[3];
  const float* wo = (const float*)d_in[4];
  float* out = (float*)d_out;

  char* ws = (char*)d_ws;
  const size_t MB = 1024 * 1024;
  float* q     = (float*)(ws);               // 4 MB
  float* k     = (float*)(ws + 4 * MB);      // 4 MB
  float* v     = (float*)(ws + 8 * MB);      // 4 MB
  float* S     = (float*)(ws + 12 * MB);     // 64 MB
  float* opart = (float*)(ws + 76 * MB);     // 64 MB
  float* mpart = (float*)(ws + 140 * MB);    // 1 MB
  float* lpart = (float*)(ws + 141 * MB);    // 1 MB  (total 142 MB)

  // K1: projections (256 row-tiles x 3 mats = 768 blocks, 3/CU, full 512 cols/block)
  k_proj<<<dim3(256, 3), 256, 0, stream>>>(x, wq, wk, wv, q, k, v);
  // K2: causal QK^T into skewed S
  k_qkt<<<BH * 136, 256, 0, stream>>>(q, k, S);
  // K3: diagonal recurrence scan
  k_scan<<<4096, 256, 0, stream>>>(S);
  // K4: split-s flash partials (16 bh * 272 units, perfectly balanced)
  k_attn_part<<<BH * 272, 256, 0, stream>>>(S, v, opart, mpart, lpart);
  // K5: combine + normalize + output projection (16 bh * 256 row-groups)
  k_combine<<<4096, 256, 0, stream>>>(opart, mpart, lpart, wo, out);
}

// Round 14
// 282.585 us; speedup vs baseline: 2.1142x; 1.0944x over previous
//
#include <hip/hip_runtime.h>
#include <hip/hip_bf16.h>
#include <math.h>

// ROSA QKV layer, fp32.
//  K1 k_proj      : q/k/v = softmax_head((x @ W)/tau), softmax fused.
//                   R13: x via LDS broadcast (verified: SGPR 80->32, VALUBusy
//                   40->65%). This round: 2-phase W register pipeline (k+=16,
//                   alternating wa/wb) removes the 32 v_mov/iter copy overhead
//                   R13 counters implied (65% busy vs 27us VALU floor).
//  K2 k_qkt       : causal QK^T into skewed coords; staging now float4
//                   (SW swizzle preserves float4 groups: XOR touches bits>=2).
//  K3 k_scan      : y[c] = x[c]*(y[c-1]+1) along skewed rows, wave shfl-scan
//  K4 k_attn_part : split-s flash partial (PV: V-in-registers, broadcast b128)
//  K5 k_combine   : merge <=16 partials per row, normalize, wo projection
//                   (wos staging vectorized to float4).
//
// ws layout: q 4MB | k 4MB | v 4MB | S 64MB | opart 64MB | mpart 1MB | lpart 1MB = 142MB

#define TT 1024
#define BB 2
#define HH 8
#define HD 64
#define DD 512
#define BH (BB*HH)

constexpr float INV_TAU = 10.0f;

// XOR swizzle for K2 fragment reads: bijective per row, float4-preserving.
#define SW(r, j) ((j) ^ ((((r) >> 2) & 7) << 2))

// ---------------- K1: projection GEMM + fused per-head softmax ----------------
// block: 8 rows x 512 cols, thread t owns cols 2t,2t+1. Half-wave = one head.
#define PROJ_FMA8(WREG, KOFF)                                            \
  _Pragma("unroll")                                                      \
  for (int r = 0; r < 8; ++r) {                                          \
    float4 x0 = *(const float4*)&xs[r * 512 + (KOFF)];                   \
    float4 x1 = *(const float4*)&xs[r * 512 + (KOFF) + 4];               \
    acc0[r] = fmaf(x0.x, WREG[0].x, acc0[r]);                            \
    acc1[r] = fmaf(x0.x, WREG[0].y, acc1[r]);                            \
    acc0[r] = fmaf(x0.y, WREG[1].x, acc0[r]);                            \
    acc1[r] = fmaf(x0.y, WREG[1].y, acc1[r]);                            \
    acc0[r] = fmaf(x0.z, WREG[2].x, acc0[r]);                            \
    acc1[r] = fmaf(x0.z, WREG[2].y, acc1[r]);                            \
    acc0[r] = fmaf(x0.w, WREG[3].x, acc0[r]);                            \
    acc1[r] = fmaf(x0.w, WREG[3].y, acc1[r]);                            \
    acc0[r] = fmaf(x1.x, WREG[4].x, acc0[r]);                            \
    acc1[r] = fmaf(x1.x, WREG[4].y, acc1[r]);                            \
    acc0[r] = fmaf(x1.y, WREG[5].x, acc0[r]);                            \
    acc1[r] = fmaf(x1.y, WREG[5].y, acc1[r]);                            \
    acc0[r] = fmaf(x1.z, WREG[6].x, acc0[r]);                            \
    acc1[r] = fmaf(x1.z, WREG[6].y, acc1[r]);                            \
    acc0[r] = fmaf(x1.w, WREG[7].x, acc0[r]);                            \
    acc1[r] = fmaf(x1.w, WREG[7].y, acc1[r]);                            \
  }

__global__ __launch_bounds__(256) void k_proj(const float* __restrict__ x,
                                              const float* __restrict__ wq,
                                              const float* __restrict__ wk,
                                              const float* __restrict__ wv,
                                              float* __restrict__ oq,
                                              float* __restrict__ ok,
                                              float* __restrict__ ov) {
  __shared__ float xs[8 * 512];
  const int tid = threadIdx.x;
  const int arr = blockIdx.y;
  const float* __restrict__ W = (arr == 0) ? wq : ((arr == 1) ? wk : wv);
  float* __restrict__ out = (arr == 0) ? oq : ((arr == 1) ? ok : ov);
  const int row0 = blockIdx.x * 8;
  const int c2 = tid * 2;

  // stage x: the 8 rows are one contiguous 4096-float span of x
  const float* __restrict__ xb = &x[(size_t)row0 * 512];
#pragma unroll
  for (int i = 0; i < 4; ++i) {
    int idx = (i * 256 + tid) * 4;
    *(float4*)&xs[idx] = *(const float4*)&xb[idx];
  }
  __syncthreads();

  float acc0[8] = {};
  float acc1[8] = {};
  float2 wa[8], wb[8];
#pragma unroll
  for (int j = 0; j < 8; ++j) wa[j] = *(const float2*)&W[(size_t)j * 512 + c2];

  // 2-phase register pipeline: no wcur<-wnxt copies (R13: movs were ~20% of VALU)
  for (int k = 0; k < 512; k += 16) {
#pragma unroll
    for (int j = 0; j < 8; ++j)
      wb[j] = *(const float2*)&W[(size_t)(k + 8 + j) * 512 + c2];
    PROJ_FMA8(wa, k)
    if (k + 16 < 512) {
#pragma unroll
      for (int j = 0; j < 8; ++j)
        wa[j] = *(const float2*)&W[(size_t)(k + 16 + j) * 512 + c2];
    }
    PROJ_FMA8(wb, k + 8)
  }

  // fused per-head softmax: half-wave = one head (32 lanes x 2 cols)
#pragma unroll
  for (int r = 0; r < 8; ++r) {
    float m = fmaxf(acc0[r], acc1[r]);
#pragma unroll
    for (int off = 16; off; off >>= 1) m = fmaxf(m, __shfl_xor(m, off));
    float e0 = __expf((acc0[r] - m) * INV_TAU);
    float e1 = __expf((acc1[r] - m) * INV_TAU);
    float s = e0 + e1;
#pragma unroll
    for (int off = 16; off; off >>= 1) s += __shfl_xor(s, off);
    float inv = 1.0f / s;
    *(float2*)&out[(size_t)(row0 + r) * 512 + c2] = make_float2(e0 * inv, e1 * inv);
  }
}

// ---------------- K2: causal QK^T into skewed layout ----------------
// S[bh][d][c] = sum_j q[bh][c+d][j] * k[bh][c][j],  valid iff d + c < T.
__global__ __launch_bounds__(256) void k_qkt(const float* __restrict__ q,
                                             const float* __restrict__ k,
                                             float* __restrict__ S) {
  int bh = blockIdx.x / 136;
  int tri = blockIdx.x - bh * 136;
  int di = 0;
  while (tri >= 16 - di) { tri -= 16 - di; ++di; }
  int cj = tri;
  int d0 = di * 64, c0 = cj * 64;
  int b = bh >> 3, h = bh & 7;

  __shared__ float ks[64][64];
  __shared__ float qs[128][64];
  int tid = threadIdx.x;

  // float4 staging (SW keeps float4 groups contiguous: XOR affects bits 2-4)
  for (int idx = tid; idx < 64 * 16; idx += 256) {
    int r = idx >> 4, j4 = (idx & 15) << 2;
    *(float4*)&ks[r][SW(r, j4)] =
        *(const float4*)&k[((size_t)(b * TT + c0 + r) * HH + h) * 64 + j4];
  }
  int tb = c0 + d0;
  for (int idx = tid; idx < 128 * 16; idx += 256) {
    int r = idx >> 4, j4 = (idx & 15) << 2;
    int t = tb + r;
    float4 val = (t < TT)
        ? *(const float4*)&q[((size_t)(b * TT + t) * HH + h) * 64 + j4]
        : make_float4(0.f, 0.f, 0.f, 0.f);
    *(float4*)&qs[r][SW(r, j4)] = val;
  }
  __syncthreads();

  int tx = tid & 15, ty = tid >> 4;
  int cl = tx * 4, dl = ty * 4;
  int qbase = cl + dl;
  float acc[4][4] = {};
  for (int j = 0; j < 64; j += 4) {
    float kv[4][4], qv[7][4];
#pragma unroll
    for (int i = 0; i < 4; ++i) {
      float4 t4 = *(const float4*)&ks[cl + i][SW(cl + i, j)];
      kv[i][0] = t4.x; kv[i][1] = t4.y; kv[i][2] = t4.z; kv[i][3] = t4.w;
    }
#pragma unroll
    for (int i = 0; i < 7; ++i) {
      float4 t4 = *(const float4*)&qs[qbase + i][SW(qbase + i, j)];
      qv[i][0] = t4.x; qv[i][1] = t4.y; qv[i][2] = t4.z; qv[i][3] = t4.w;
    }
#pragma unroll
    for (int jj = 0; jj < 4; ++jj)
#pragma unroll
      for (int m = 0; m < 4; ++m)
#pragma unroll
        for (int i = 0; i < 4; ++i)
          acc[m][i] = fmaf(qv[m + i][jj], kv[i][jj], acc[m][i]);
  }

  float* Sb = S + (size_t)bh * TT * TT;
#pragma unroll
  for (int m = 0; m < 4; ++m) {
    int d = d0 + dl + m;
#pragma unroll
    for (int i = 0; i < 4; ++i) {
      int c = c0 + cl + i;
      if (d + c < TT) Sb[(size_t)d * TT + c] = acc[m][i];
    }
  }
}

// ---------------- K3: recurrence scan along skewed rows ----------------
__global__ __launch_bounds__(256) void k_scan(float* __restrict__ S) {
  int gw = (blockIdx.x * 256 + threadIdx.x) >> 6;   // 0..16383
  int lane = threadIdx.x & 63;
  int bh = gw >> 10;
  int d = gw & 1023;
  float* row = S + (size_t)bh * TT * TT + (size_t)d * TT;
  int len = TT - d;
  float carry = 0.0f;
  for (int c0 = 0; c0 < len; c0 += 64) {
    int c = c0 + lane;
    bool act = (c < len);
    float xv = act ? row[c] : 0.0f;
    float G = xv, A = xv;
#pragma unroll
    for (int off = 1; off < 64; off <<= 1) {
      float gp = __shfl_up(G, off);
      float ap = __shfl_up(A, off);
      if (lane >= off) { A = fmaf(G, ap, A); G *= gp; }
    }
    float y = fmaf(G, carry, A);
    if (act) row[c] = y;
    carry = __shfl(y, 63);
  }
}

// ---------------- K4: split-s flash partial (LDS-traffic-minimized) ----------------
// block = (bh, 32-row t-tile tt, s-chunk ci). All rows satisfy t >= s0 by construction.
__global__ __launch_bounds__(256) void k_attn_part(const float* __restrict__ S,
                                                   const float* __restrict__ v,
                                                   float* __restrict__ opart,
                                                   float* __restrict__ mpart,
                                                   float* __restrict__ lpart) {
  int bh = blockIdx.x / 272;
  int u = blockIdx.x - bh * 272;
  int tt = 0;
  while (true) { int nch = (tt + 2) >> 1; if (u < nch) break; u -= nch; ++tt; }
  int ci = u;
  int t0 = tt * 32, s0 = ci * 64;
  int b = bh >> 3, h = bh & 7;

  __shared__ float As[32][64];
  __shared__ float vs[64][64];
  int tid = threadIdx.x;
  int wv = tid >> 6, lane = tid & 63;

  // stage V with float4 (4 iterations)
  for (int idx = tid; idx < 64 * 16; idx += 256) {
    int sl = idx >> 4, e4 = (idx & 15) << 2;
    *(float4*)&vs[sl][e4] =
        *(const float4*)&v[((size_t)(b * TT + s0 + sl) * HH + h) * 64 + e4];
  }
  // parallelogram gather (diagonal-major: coalesced global reads)
  const float* Sb = S + (size_t)bh * TT * TT;
  int dbase = t0 - s0 - 63;
  for (int idx = tid; idx < 95 * 64; idx += 256) {
    int dd = idx >> 6, sl = idx & 63;
    int d = dbase + dd;
    if (d < 0) continue;
    int tl = d + sl + s0 - t0;
    if (tl < 0 || tl >= 32) continue;
    As[tl][sl] = Sb[(size_t)d * TT + s0 + sl];
  }
  __syncthreads();

  int tlb = wv * 8;
  // softmax per row (lane = s); masked lanes gated by predicate, p written to As
  for (int r = 0; r < 8; ++r) {
    int tl = tlb + r;
    int t = t0 + tl;
    float inv_t1 = 1.0f / (float)(t + 1);
    bool okl = (s0 + lane <= t);
    float sc = okl ? As[tl][lane] + (float)(s0 + lane) * inv_t1 : -1e30f;
    float mt = sc;
#pragma unroll
    for (int off = 32; off; off >>= 1) mt = fmaxf(mt, __shfl_xor(mt, off));
    float p = __expf((sc - mt) * INV_TAU);     // masked lanes -> 0
    float lsum = p;
#pragma unroll
    for (int off = 32; off; off >>= 1) lsum += __shfl_xor(lsum, off);
    As[tl][lane] = p;                          // covers all 64 lanes
    if (lane == 0) {
      size_t pidx = (size_t)(bh * TT + t) * 16 + ci;
      mpart[pidx] = mt; lpart[pidx] = lsum;
    }
  }
  // PV: s-quad outer, V cached in registers, rows inner via broadcast b128.
  float o[8] = {};
  for (int sl = 0; sl < 64; sl += 4) {
    float v0 = vs[sl + 0][lane];
    float v1 = vs[sl + 1][lane];
    float v2 = vs[sl + 2][lane];
    float v3 = vs[sl + 3][lane];
#pragma unroll
    for (int r = 0; r < 8; ++r) {
      float4 pq = *(const float4*)&As[tlb + r][sl];
      o[r] = fmaf(pq.x, v0, o[r]);
      o[r] = fmaf(pq.y, v1, o[r]);
      o[r] = fmaf(pq.z, v2, o[r]);
      o[r] = fmaf(pq.w, v3, o[r]);
    }
  }
#pragma unroll
  for (int r = 0; r < 8; ++r) {
    int t = t0 + tlb + r;
    opart[((size_t)(bh * TT + t) * 16 + ci) * 64 + lane] = o[r];
  }
}

// ---------------- K5: combine partials + normalize + wo projection ----------------
__global__ __launch_bounds__(256) void k_combine(const float* __restrict__ opart,
                                                 const float* __restrict__ mpart,
                                                 const float* __restrict__ lpart,
                                                 const float* __restrict__ wo,
                                                 float* __restrict__ out) {
  int bh = blockIdx.x >> 8;          // 16 bh x 256 t-groups
  int tg = blockIdx.x & 255;
  int b = bh >> 3, h = bh & 7;
  int tid = threadIdx.x;
  int wv = tid >> 6, lane = tid & 63;

  __shared__ float wos[64][64];
  for (int idx = tid; idx < 1024; idx += 256)
    *(float4*)&(&wos[0][0])[idx << 2] =
        *(const float4*)&wo[(size_t)h * 4096 + (idx << 2)];
  __syncthreads();

  int t = tg * 4 + wv;
  int nc = (t >> 6) + 1;
  size_t base = (size_t)(bh * TT + t) * 16;

  float m = (lane < nc) ? mpart[base + lane] : -3e30f;
  float M = m;
#pragma unroll
  for (int off = 32; off; off >>= 1) M = fmaxf(M, __shfl_xor(M, off));
  float w = (lane < nc) ? __expf((m - M) * INV_TAU) : 0.0f;
  float lv = (lane < nc) ? lpart[base + lane] : 0.0f;
  float Lp = lv * w;
#pragma unroll
  for (int off = 32; off; off >>= 1) Lp += __shfl_xor(Lp, off);

  float o = 0.0f;
  for (int i = 0; i < nc; ++i) {
    float wi = __shfl(w, i);
    o = fmaf(wi, opart[(base + i) * 64 + lane], o);
  }
  float on = o / Lp;

  float res = 0.0f;
#pragma unroll 8
  for (int e = 0; e < 64; ++e)
    res = fmaf(__shfl(on, e), wos[e][lane], res);
  out[((size_t)(b * TT + t)) * 512 + h * 64 + lane] = res;
}

extern "C" void kernel_launch(void* const* d_in, const int* in_sizes, int n_in,
                              void* d_out, int out_size, void* d_ws, size_t ws_size,
                              hipStream_t stream) {
  const float* x  = (const float*)d_in[0];
  const float* wq = (const float*)d_in[1];
  const float* wk = (const float*)d_in[2];
  const float* wv = (const float*)d_in[3];
  const float* wo = (const float*)d_in[4];
  float* out = (float*)d_out;

  char* ws = (char*)d_ws;
  const size_t MB = 1024 * 1024;
  float* q     = (float*)(ws);               // 4 MB
  float* k     = (float*)(ws + 4 * MB);      // 4 MB
  float* v     = (float*)(ws + 8 * MB);      // 4 MB
  float* S     = (float*)(ws + 12 * MB);     // 64 MB
  float* opart = (float*)(ws + 76 * MB);     // 64 MB
  float* mpart = (float*)(ws + 140 * MB);    // 1 MB
  float* lpart = (float*)(ws + 141 * MB);    // 1 MB  (total 142 MB)

  // K1: projections (256 row-tiles x 3 mats = 768 blocks, 3/CU)
  k_proj<<<dim3(256, 3), 256, 0, stream>>>(x, wq, wk, wv, q, k, v);
  // K2: causal QK^T into skewed S
  k_qkt<<<BH * 136, 256, 0, stream>>>(q, k, S);
  // K3: diagonal recurrence scan
  k_scan<<<4096, 256, 0, stream>>>(S);
  // K4: split-s flash partials (16 bh * 272 units, perfectly balanced)
  k_attn_part<<<BH * 272, 256, 0, stream>>>(S, v, opart, mpart, lpart);
  // K5: combine + normalize + output projection (16 bh * 256 row-groups)
  k_combine<<<4096, 256, 0, stream>>>(opart, mpart, lpart, wo, out);
}